// Round 5
// baseline (1091.386 us; speedup 1.0000x reference)
//
#include <hip/hip_runtime.h>
#include <hip/hip_bf16.h>
#include <hip/hip_fp16.h>
#include <cstdint>

#define SENT_LEN   256
#define SENT_BATCH 64
#define WORD_LEN   16
#define EMB        128
#define HID        256
#define CEMB       64
#define CHID       128
#define TAGS       50
#define K_IN       (EMB + CHID)   // 256
#define LOG2E      1.44269504f
#define N2LOG2E    -2.88539008f   // -2*log2(e)

typedef __attribute__((ext_vector_type(8))) short short8;
typedef __attribute__((ext_vector_type(4))) float f32x4;
typedef __attribute__((ext_vector_type(4))) int   i32x4;
typedef __attribute__((ext_vector_type(2))) long  lng2;

__device__ __forceinline__ float rcpf(float x) { return __builtin_amdgcn_rcpf(x); }
// inputs pre-scaled by log2e: sig2(xl) = sigmoid(xl/log2e)
__device__ __forceinline__ float sig2(float xl) {
    return rcpf(1.f + __builtin_amdgcn_exp2f(-xl));
}
// tanh via sigmoid identity, clamp-free: tanh(x) = 2*sigmoid(2x)-1.
__device__ __forceinline__ float tanh2(float xl) {
    float e = __builtin_amdgcn_exp2f(-(xl + xl));
    return 2.f * rcpf(1.f + e) - 1.f;
}
__device__ __forceinline__ float lstm_act(float gi, float gf, float gg, float go, float& cst) {
    float c = sig2(gf) * cst + sig2(gi) * tanh2(gg);
    cst = c;
    float tc = 2.f * rcpf(1.f + __builtin_amdgcn_exp2f(N2LOG2E * c)) - 1.f;
    return sig2(go) * tc;
}
__device__ __forceinline__ float bf_lo(unsigned u) { return __uint_as_float(u << 16); }
__device__ __forceinline__ float bf_hi(unsigned u) { return __uint_as_float(u & 0xffff0000u); }
// branch-free RNE bf16 (finite inputs only)
__device__ __forceinline__ unsigned short f2bfu(float f) {
    unsigned u = __float_as_uint(f);
    u += 0x7fff + ((u >> 16) & 1);
    return (unsigned short)(u >> 16);
}
// CK-style barrier: drains LDS (lgkmcnt) only — global prefetches stay in flight.
__device__ __forceinline__ void block_sync_lds() {
    asm volatile("s_waitcnt lgkmcnt(0)\ns_barrier" ::: "memory");
}
// 16-byte K-fragment MFMA as two K=32 i8 calls (word_lstm path).
__device__ __forceinline__ i32x4 mfma_i8_k64(lng2 a, lng2 b, i32x4 c) {
    c = __builtin_amdgcn_mfma_i32_16x16x32_i8(a.x, b.x, c, 0, 0, 0);
    return __builtin_amdgcn_mfma_i32_16x16x32_i8(a.y, b.y, c, 0, 0, 0);
}
// quad_perm broadcast of quad-lane Q (pure-VALU cross-lane, no LDS pipe)
template<int Q> __device__ __forceinline__ float qbcast(float x) {
    return __int_as_float(__builtin_amdgcn_mov_dpp(
        __float_as_int(x), Q * 0x55, 0xF, 0xF, false));
}
__device__ __forceinline__ __half2 h2bits(int b) {
    return __builtin_bit_cast(__half2, b);
}

// ---------------- K1a: pre8[ch*512 + (j*4+gt)] = s_e * LOG2E*(b_c[g] + Wih_c[g]·char_emb[ch])
// s_e = -2 for the g-gate (tanh), -1 otherwise: folds the exp2 argument scale in.
__global__ void prep_char(const float* __restrict__ Wih_c, const float* __restrict__ char_emb,
                          const float* __restrict__ bih_c, const float* __restrict__ bhh_c,
                          float* __restrict__ pre8) {
    int ch = blockIdx.x;      // 128
    int g  = threadIdx.x;     // 512
    float acc = bih_c[g] + bhh_c[g];
    const float* w = Wih_c + g * CEMB;
    const float* e = char_emb + ch * CEMB;
#pragma unroll
    for (int k = 0; k < CEMB; k++) acc += w[k] * e[k];
    int gt = g >> 7, j = g & 127;
    float s_e = (gt == 2) ? -2.f : -1.f;
    pre8[((ch * 128) + j) * 4 + gt] = acc * LOG2E * s_e;
}

// ---------------- K1b: per-row i8 quantization of Whh_w. 1024 blocks x 64.
__global__ void prep_wq(const float* __restrict__ Whh_w, signed char* __restrict__ wq,
                        float* __restrict__ sw) {
    int g = blockIdx.x;
    int lane = threadIdx.x;   // 64
    float4 v = reinterpret_cast<const float4*>(Whh_w + (size_t)g * HID)[lane];
    float m = fmaxf(fmaxf(fabsf(v.x), fabsf(v.y)), fmaxf(fabsf(v.z), fabsf(v.w)));
#pragma unroll
    for (int off = 32; off; off >>= 1) m = fmaxf(m, __shfl_xor(m, off, 64));
    m = fmaxf(m, 1e-20f);
    float inv = 127.f / m;
    int q0 = __float2int_rn(v.x * inv), q1 = __float2int_rn(v.y * inv);
    int q2 = __float2int_rn(v.z * inv), q3 = __float2int_rn(v.w * inv);
    int packed = (q0 & 255) | ((q1 & 255) << 8) | ((q2 & 255) << 16) | ((q3 & 255) << 24);
    reinterpret_cast<int*>(wq)[g * 64 + lane] = packed;
    if (lane == 0) sw[g] = m / 127.f;
}

// ---------------- K2: char LSTM, f16 pk_fma form. 256 blocks x 1 chain, 512 threads.
// ONE GATE PER LANE: lane = 4*j_local + nt (R0 layout). h kept in LDS as f16 (256 B/buf);
// weights as 64 resident __half2. Dot = 64 v_pk_fma_f16 (full-rate, 8 rotating accs)
// instead of 32 quarter-rate sdot4 — issue ~480 -> ~150 cyc/lane. f16 direct weights
// (rel 5e-4) replace i8 quant (abs ~4e-3 on h): accuracy equal or better.
__global__ __launch_bounds__(512, 1) void char_lstm(
        const int* __restrict__ words, const float* __restrict__ Whh_c,
        const float* __restrict__ pre8, float* __restrict__ cf) {
    int t    = blockIdx.x;               // chain
    int tid  = threadIdx.x;
    int lane = tid & 63, w = tid >> 6;   // 8 waves
    int nt   = lane & 3;
    int j    = w * 16 + (lane >> 2);
    int g    = nt * 128 + j;             // this lane's gate row

    __shared__ __align__(16) __half hv[2][128];   // h as f16, dbuf, 512 B

    // ---- weights: direct f32->f16 convert, VGPR-resident
    const float4* wr = reinterpret_cast<const float4*>(Whh_c + (size_t)g * CHID);
    __half2 wh2[64];
#pragma unroll
    for (int q = 0; q < 32; q++) {
        float4 f = wr[q];
        wh2[q * 2]     = __floats2half2_rn(f.x, f.y);
        wh2[q * 2 + 1] = __floats2half2_rn(f.z, f.w);
    }
    float s_e = (nt == 2) ? -2.f : -1.f;
    float sca = s_e * LOG2E;             // dot-term scale (pre8 already carries its own)
    float m_a = (nt == 2) ?  2.f :  1.f;
    float b_a = (nt == 2) ? -1.f :  0.f;

    if (tid < 128) { reinterpret_cast<int*>(hv)[tid] = 0; }

    float cst = 0.f;
    int cid0 = words[t];
    int cid1 = words[SENT_LEN + t];
    float pl0 = pre8[(size_t)cid0 * 512 + tid];   // this lane's gate pre-input
    float pl1 = pre8[(size_t)cid1 * 512 + tid];
    int ci2 = words[2 * SENT_LEN + t];
    int ci3 = words[3 * SENT_LEN + t];
    __syncthreads();

    for (int u = 0; u < 512; u++) {          // steps 2u (A), 2u+1 (B)
        float pf0 = pre8[(size_t)ci2 * 512 + tid];
        float pf1 = pre8[(size_t)ci3 * 512 + tid];
        ci2 = words[(((u << 1) + 4) & 1023) * SENT_LEN + t];
        ci3 = words[(((u << 1) + 5) & 1023) * SENT_LEN + t];

        {   // step A: read hv[0] -> write hv[1]
            const i32x4* hp4 = reinterpret_cast<const i32x4*>(hv[0]);
            __half2 a0 = __float2half2_rn(0.f), a1 = a0, a2 = a0, a3 = a0;
            __half2 a4 = a0, a5 = a0, a6 = a0, a7 = a0;
#pragma unroll
            for (int q = 0; q < 16; q += 2) {
                i32x4 hq = hp4[q];
                a0 = __hfma2(h2bits(hq.x), wh2[q * 4 + 0], a0);
                a1 = __hfma2(h2bits(hq.y), wh2[q * 4 + 1], a1);
                a2 = __hfma2(h2bits(hq.z), wh2[q * 4 + 2], a2);
                a3 = __hfma2(h2bits(hq.w), wh2[q * 4 + 3], a3);
                i32x4 hr = hp4[q + 1];
                a4 = __hfma2(h2bits(hr.x), wh2[q * 4 + 4], a4);
                a5 = __hfma2(h2bits(hr.y), wh2[q * 4 + 5], a5);
                a6 = __hfma2(h2bits(hr.z), wh2[q * 4 + 6], a6);
                a7 = __hfma2(h2bits(hr.w), wh2[q * 4 + 7], a7);
            }
            __half2 s03 = __hadd2(__hadd2(a0, a1), __hadd2(a2, a3));
            __half2 s47 = __hadd2(__hadd2(a4, a5), __hadd2(a6, a7));
            float s = (__low2float(s03) + __high2float(s03))
                    + (__low2float(s47) + __high2float(s47));
            float e  = __builtin_amdgcn_exp2f(fmaf(s, sca, pl0));
            float av = m_a * rcpf(1.f + e) + b_a;
            float qi = qbcast<0>(av), qf = qbcast<1>(av);
            float qg = qbcast<2>(av), qo = qbcast<3>(av);
            float cv = fmaf(qf, cst, qi * qg); cst = cv;
            float tc = 2.f * rcpf(1.f + __builtin_amdgcn_exp2f(N2LOG2E * cv)) - 1.f;
            float h  = qo * tc;
            if (nt == 0)
                hv[1][j] = __float2half_rn(h);
            block_sync_lds();
        }
        {   // step B: read hv[1] -> write hv[0]
            const i32x4* hp4 = reinterpret_cast<const i32x4*>(hv[1]);
            __half2 a0 = __float2half2_rn(0.f), a1 = a0, a2 = a0, a3 = a0;
            __half2 a4 = a0, a5 = a0, a6 = a0, a7 = a0;
#pragma unroll
            for (int q = 0; q < 16; q += 2) {
                i32x4 hq = hp4[q];
                a0 = __hfma2(h2bits(hq.x), wh2[q * 4 + 0], a0);
                a1 = __hfma2(h2bits(hq.y), wh2[q * 4 + 1], a1);
                a2 = __hfma2(h2bits(hq.z), wh2[q * 4 + 2], a2);
                a3 = __hfma2(h2bits(hq.w), wh2[q * 4 + 3], a3);
                i32x4 hr = hp4[q + 1];
                a4 = __hfma2(h2bits(hr.x), wh2[q * 4 + 4], a4);
                a5 = __hfma2(h2bits(hr.y), wh2[q * 4 + 5], a5);
                a6 = __hfma2(h2bits(hr.z), wh2[q * 4 + 6], a6);
                a7 = __hfma2(h2bits(hr.w), wh2[q * 4 + 7], a7);
            }
            __half2 s03 = __hadd2(__hadd2(a0, a1), __hadd2(a2, a3));
            __half2 s47 = __hadd2(__hadd2(a4, a5), __hadd2(a6, a7));
            float s = (__low2float(s03) + __high2float(s03))
                    + (__low2float(s47) + __high2float(s47));
            float e  = __builtin_amdgcn_exp2f(fmaf(s, sca, pl1));
            float av = m_a * rcpf(1.f + e) + b_a;
            float qi = qbcast<0>(av), qf = qbcast<1>(av);
            float qg = qbcast<2>(av), qo = qbcast<3>(av);
            float cv = fmaf(qf, cst, qi * qg); cst = cv;
            float tc = 2.f * rcpf(1.f + __builtin_amdgcn_exp2f(N2LOG2E * cv)) - 1.f;
            float h  = qo * tc;
            if (nt == 0) {
                hv[0][j] = __float2half_rn(h);
                if ((u & 7) == 7)
                    cf[((size_t)t * SENT_BATCH + (u >> 3)) * CHID + j] = h;
            }
            block_sync_lds();
        }
        pl0 = pf0; pl1 = pf1;
    }
}

// ---------------- K3: bf16 MFMA GEMM (R12 form). xw8[(b*256+t)*256+j] = uint2{bf16 gates}.
#define XW_SEG 65   // 16B units per LDS segment (64 lanes + 1 pad)
__global__ __launch_bounds__(256, 2) void xw_gemm(
        const int* __restrict__ sentences, const float* __restrict__ word_emb,
        const float* __restrict__ cf, const float* __restrict__ Wih_w,
        const float* __restrict__ bih_w, const float* __restrict__ bhh_w,
        uint2* __restrict__ xw8) {
    __shared__ short8 Apack[32 * XW_SEG];   // segment s = kt*4 + wv(m-tile)
    __shared__ short8 Bpack[32 * XW_SEG];   // segment s = kt*4 + nt(gate type)
    __shared__ int sid_s[64];
    int tid = threadIdx.x;
    int j0 = blockIdx.x * 16;
    int row0 = blockIdx.y * 64;             // row0 = t*64: whole block is one t
    if (tid < 64) sid_s[tid] = sentences[row0 + tid];
    __syncthreads();

#pragma unroll
    for (int it = 0; it < 8; it++) {
        int idx = it * 256 + tid;
        int m = idx >> 5, k8 = idx & 31;
        int k = k8 * 8;
        int kt = k8 >> 2, lqs = k8 & 3;
        int lanes = (m & 15) + (lqs << 4);
        int seg = kt * 4 + (m >> 4);
        const float* asrc = (k < EMB)
            ? word_emb + (size_t)sid_s[m] * EMB + k
            : cf + (size_t)(row0 + m) * CHID + (k - EMB);
        float4 a0 = reinterpret_cast<const float4*>(asrc)[0];
        float4 a1 = reinterpret_cast<const float4*>(asrc)[1];
        short8 av;
        av[0] = (short)f2bfu(a0.x); av[1] = (short)f2bfu(a0.y);
        av[2] = (short)f2bfu(a0.z); av[3] = (short)f2bfu(a0.w);
        av[4] = (short)f2bfu(a1.x); av[5] = (short)f2bfu(a1.y);
        av[6] = (short)f2bfu(a1.z); av[7] = (short)f2bfu(a1.w);
        Apack[seg * XW_SEG + lanes] = av;
        const float* bsrc = Wih_w + (size_t)((m >> 4) * 256 + j0 + (m & 15)) * K_IN + k;
        float4 b0 = reinterpret_cast<const float4*>(bsrc)[0];
        float4 b1 = reinterpret_cast<const float4*>(bsrc)[1];
        short8 bv;
        bv[0] = (short)f2bfu(b0.x); bv[1] = (short)f2bfu(b0.y);
        bv[2] = (short)f2bfu(b0.z); bv[3] = (short)f2bfu(b0.w);
        bv[4] = (short)f2bfu(b1.x); bv[5] = (short)f2bfu(b1.y);
        bv[6] = (short)f2bfu(b1.z); bv[7] = (short)f2bfu(b1.w);
        Bpack[seg * XW_SEG + lanes] = bv;
    }
    __syncthreads();

    int lane = tid & 63, wv = tid >> 6, l15 = lane & 15, lq = lane >> 4;
    f32x4 acc[4] = {{0.f,0.f,0.f,0.f},{0.f,0.f,0.f,0.f},{0.f,0.f,0.f,0.f},{0.f,0.f,0.f,0.f}};
#pragma unroll
    for (int kt = 0; kt < 8; kt++) {
        short8 a = Apack[(kt * 4 + wv) * XW_SEG + lane];
#pragma unroll
        for (int nt = 0; nt < 4; nt++)
            acc[nt] = __builtin_amdgcn_mfma_f32_16x16x32_bf16(
                a, Bpack[(kt * 4 + nt) * XW_SEG + lane], acc[nt], 0, 0, 0);
    }
    float bb[4];
#pragma unroll
    for (int nt = 0; nt < 4; nt++)
        bb[nt] = bih_w[nt * 256 + j0 + l15] + bhh_w[nt * 256 + j0 + l15];
    int t = row0 >> 6;
#pragma unroll
    for (int r = 0; r < 4; r++) {
        int b = wv * 16 + lq * 4 + r;       // chain index within this t
        uint2 o;
        o.x = (unsigned)f2bfu((acc[0][r] + bb[0]) * LOG2E)
            | ((unsigned)f2bfu((acc[1][r] + bb[1]) * LOG2E) << 16);
        o.y = (unsigned)f2bfu((acc[2][r] + bb[2]) * LOG2E)
            | ((unsigned)f2bfu((acc[3][r] + bb[3]) * LOG2E) << 16);
        xw8[((size_t)b * SENT_LEN + t) * 256 + j0 + l15] = o;
    }
}

// ---------------- K4: word LSTM. 64 blocks x 1 chain, 1024 threads (16 waves).
__global__ __launch_bounds__(1024, 1) void word_lstm(
        const uint2* __restrict__ xw8, const signed char* __restrict__ wq,
        const float* __restrict__ sw, float* __restrict__ h_out) {
    int b    = blockIdx.x;               // chain 0..63
    int tid  = threadIdx.x;
    int lane = tid & 63, w = tid >> 6;   // 16 waves
    int l15  = lane & 15, lq = lane >> 4;
    int j    = w * 16 + l15;

    __shared__ __align__(16) signed char hv[2][256];   // h as i8, dbuf, 512 B

    lng2 bfr[4][4];
    float swl[4];
#pragma unroll
    for (int nt = 0; nt < 4; nt++) {
        int g = nt * 256 + j;
        swl[nt] = sw[g] * (LOG2E / 127.f);
#pragma unroll
        for (int kt = 0; kt < 4; kt++)
            bfr[nt][kt] = reinterpret_cast<const lng2*>(wq + (size_t)g * HID + kt * 64 + lq * 16)[0];
    }
    if (tid < 128) { reinterpret_cast<int*>(hv)[tid] = 0; }

    const uint2* xwb = xw8 + (size_t)b * SENT_LEN * 256;   // this block's stream
    float cst = 0.f;
    uint2 xq0 = xwb[0 * 256 + j];
    uint2 xq1 = xwb[1 * 256 + j];
    uint2 xq2 = xwb[2 * 256 + j];
    uint2 xq3 = xwb[3 * 256 + j];
    __syncthreads();

    for (int u = 0; u < 128; u++) {          // steps 2u (A), 2u+1 (B)
        uint2 xn0 = xwb[((((u << 1) + 4) & 255)) * 256 + j];
        uint2 xn1 = xwb[((((u << 1) + 5) & 255)) * 256 + j];

        {   // step A: read hv[0] -> write hv[1]
            const lng2* hp = reinterpret_cast<const lng2*>(hv[0]);
            i32x4 acc[4] = {};
#pragma unroll
            for (int kt = 0; kt < 4; kt++) {
                lng2 a = hp[kt * 4 + lq];
#pragma unroll
                for (int nt = 0; nt < 4; nt++)
                    acc[nt] = mfma_i8_k64(a, bfr[nt][kt], acc[nt]);
            }
            float gi = (float)acc[0][0] * swl[0] + bf_lo(xq0.x);
            float gf = (float)acc[1][0] * swl[1] + bf_hi(xq0.x);
            float gg = (float)acc[2][0] * swl[2] + bf_lo(xq0.y);
            float go = (float)acc[3][0] * swl[3] + bf_hi(xq0.y);
            float h = lstm_act(gi, gf, gg, go, cst);
            if (lq == 0) {
                h_out[((size_t)(u << 1) * SENT_BATCH + b) * HID + j] = h;
                hv[1][j] = (signed char)__float2int_rn(h * 127.f);
            }
            block_sync_lds();
        }
        {   // step B: read hv[1] -> write hv[0]
            const lng2* hp = reinterpret_cast<const lng2*>(hv[1]);
            i32x4 acc[4] = {};
#pragma unroll
            for (int kt = 0; kt < 4; kt++) {
                lng2 a = hp[kt * 4 + lq];
#pragma unroll
                for (int nt = 0; nt < 4; nt++)
                    acc[nt] = mfma_i8_k64(a, bfr[nt][kt], acc[nt]);
            }
            float gi = (float)acc[0][0] * swl[0] + bf_lo(xq1.x);
            float gf = (float)acc[1][0] * swl[1] + bf_hi(xq1.x);
            float gg = (float)acc[2][0] * swl[2] + bf_lo(xq1.y);
            float go = (float)acc[3][0] * swl[3] + bf_hi(xq1.y);
            float h = lstm_act(gi, gf, gg, go, cst);
            if (lq == 0) {
                h_out[((size_t)((u << 1) + 1) * SENT_BATCH + b) * HID + j] = h;
                hv[0][j] = (signed char)__float2int_rn(h * 127.f);
            }
            block_sync_lds();
        }
        xq0 = xq2; xq1 = xq3; xq2 = xn0; xq3 = xn1;
    }
}

// ---------------- K5: tag projection + log_softmax. 8 rows/block (W_tag staging amortized).
__global__ __launch_bounds__(256) void tag_logsoftmax(
        const float* __restrict__ h_out, const float* __restrict__ W_tag,
        const float* __restrict__ b_tag, float* __restrict__ out) {
    __shared__ float wt_s[TAGS * 257];      // 51.4 KB
    __shared__ float hr_s[8 * HID];         // 8 KB
    int tid = threadIdx.x;
    int row0 = blockIdx.x * 8;
#pragma unroll 2
    for (int i = 0; i < TAGS; i++) wt_s[i * 257 + tid] = W_tag[i * HID + tid];
#pragma unroll
    for (int w = 0; w < 8; w++) hr_s[w * HID + tid] = h_out[(size_t)(row0 + w) * HID + tid];
    __syncthreads();

    int w4 = tid >> 6, l = tid & 63;
#pragma unroll
    for (int rep = 0; rep < 2; rep++) {
        int w = rep * 4 + w4;
        float acc = 0.f;
        if (l < TAGS) {
            acc = b_tag[l];
            const float* hr = hr_s + w * HID;
            const float* wr = wt_s + l * 257;
#pragma unroll 4
            for (int k = 0; k < HID; k++) acc += hr[k] * wr[k];
        }
        float m = (l < TAGS) ? acc : -1e30f;
#pragma unroll
        for (int off = 32; off; off >>= 1) m = fmaxf(m, __shfl_xor(m, off, 64));
        float e = (l < TAGS) ? __builtin_amdgcn_exp2f((acc - m) * LOG2E) : 0.f;
        float ssum = e;
#pragma unroll
        for (int off = 32; off; off >>= 1) ssum += __shfl_xor(ssum, off, 64);
        float lse = m + __logf(ssum);
        if (l < TAGS) out[(size_t)(row0 + w) * TAGS + l] = acc - lse;
    }
}

extern "C" void kernel_launch(void* const* d_in, const int* in_sizes, int n_in,
                              void* d_out, int out_size, void* d_ws, size_t ws_size,
                              hipStream_t stream) {
    (void)in_sizes; (void)n_in; (void)out_size; (void)ws_size;
    const int*   sentences = (const int*)d_in[0];
    const int*   words     = (const int*)d_in[1];
    const float* word_emb  = (const float*)d_in[4];
    const float* char_emb  = (const float*)d_in[5];
    const float* Wih_c     = (const float*)d_in[6];
    const float* Whh_c     = (const float*)d_in[7];
    const float* bih_c     = (const float*)d_in[8];
    const float* bhh_c     = (const float*)d_in[9];
    const float* Wih_w     = (const float*)d_in[10];
    const float* Whh_w     = (const float*)d_in[11];
    const float* bih_w     = (const float*)d_in[12];
    const float* bhh_w     = (const float*)d_in[13];
    const float* W_tag     = (const float*)d_in[14];
    const float* b_tag     = (const float*)d_in[15];
    float* out = (float*)d_out;

    char* ws = (char*)d_ws;
    size_t off = 0;
    float* pre8 = (float*)(ws + off);                 off += 128 * 512 * sizeof(float);      // 256 KB
    signed char* wq = (signed char*)(ws + off);       off += 1024 * 256;                     // 256 KB
    float* sw = (float*)(ws + off);                   off += 1024 * sizeof(float);           // 4 KB
    off = (off + 255) & ~(size_t)255;
    float* cf = (float*)(ws + off);                   off += (size_t)SENT_LEN * SENT_BATCH * CHID * sizeof(float); // 8.4 MB
    uint2* xw8 = (uint2*)(ws + off);                  off += (size_t)SENT_LEN * SENT_BATCH * 256 * sizeof(uint2);  // 33.5 MB
    float* h_out = (float*)(ws + off);                off += (size_t)SENT_LEN * SENT_BATCH * HID * sizeof(float);  // 16.8 MB

    hipLaunchKernelGGL(prep_char, dim3(128), dim3(512), 0, stream,
                       Wih_c, char_emb, bih_c, bhh_c, pre8);
    hipLaunchKernelGGL(prep_wq, dim3(1024), dim3(64), 0, stream, Whh_w, wq, sw);
    hipLaunchKernelGGL(char_lstm, dim3(256), dim3(512), 0, stream,
                       words, Whh_c, pre8, cf);
    hipLaunchKernelGGL(xw_gemm, dim3(16, 256), dim3(256), 0, stream,
                       sentences, word_emb, cf, Wih_w, bih_w, bhh_w, xw8);
    hipLaunchKernelGGL(word_lstm, dim3(SENT_BATCH), dim3(1024), 0, stream,
                       xw8, wq, sw, h_out);
    hipLaunchKernelGGL(tag_logsoftmax, dim3((SENT_LEN * SENT_BATCH) / 8), dim3(256), 0, stream,
                       h_out, W_tag, b_tag, out);
}

// Round 6
// 1014.423 us; speedup vs baseline: 1.0759x; 1.0759x over previous
//
#include <hip/hip_runtime.h>
#include <hip/hip_bf16.h>
#include <cstdint>

#define SENT_LEN   256
#define SENT_BATCH 64
#define WORD_LEN   16
#define EMB        128
#define HID        256
#define CEMB       64
#define CHID       128
#define TAGS       50
#define K_IN       (EMB + CHID)   // 256
#define LOG2E      1.44269504f
#define N2LOG2E    -2.88539008f   // -2*log2(e)

typedef __attribute__((ext_vector_type(8))) short short8;
typedef __attribute__((ext_vector_type(4))) float f32x4;
typedef __attribute__((ext_vector_type(4))) int   i32x4;
typedef __attribute__((ext_vector_type(2))) long  lng2;

__device__ __forceinline__ float rcpf(float x) { return __builtin_amdgcn_rcpf(x); }
// inputs pre-scaled by log2e: sig2(xl) = sigmoid(xl/log2e)
__device__ __forceinline__ float sig2(float xl) {
    return rcpf(1.f + __builtin_amdgcn_exp2f(-xl));
}
// tanh via sigmoid identity, clamp-free: tanh(x) = 2*sigmoid(2x)-1.
__device__ __forceinline__ float tanh2(float xl) {
    float e = __builtin_amdgcn_exp2f(-(xl + xl));
    return 2.f * rcpf(1.f + e) - 1.f;
}
__device__ __forceinline__ float lstm_act(float gi, float gf, float gg, float go, float& cst) {
    float c = sig2(gf) * cst + sig2(gi) * tanh2(gg);
    cst = c;
    float tc = 2.f * rcpf(1.f + __builtin_amdgcn_exp2f(N2LOG2E * c)) - 1.f;
    return sig2(go) * tc;
}
__device__ __forceinline__ float bf_lo(unsigned u) { return __uint_as_float(u << 16); }
__device__ __forceinline__ float bf_hi(unsigned u) { return __uint_as_float(u & 0xffff0000u); }
// branch-free RNE bf16 (finite inputs only)
__device__ __forceinline__ unsigned short f2bfu(float f) {
    unsigned u = __float_as_uint(f);
    u += 0x7fff + ((u >> 16) & 1);
    return (unsigned short)(u >> 16);
}
// CK-style barrier: drains LDS (lgkmcnt) only — global prefetches stay in flight.
__device__ __forceinline__ void block_sync_lds() {
    asm volatile("s_waitcnt lgkmcnt(0)\ns_barrier" ::: "memory");
}
// 16-byte K-fragment MFMA as two K=32 i8 calls (word_lstm path).
__device__ __forceinline__ i32x4 mfma_i8_k64(lng2 a, lng2 b, i32x4 c) {
    c = __builtin_amdgcn_mfma_i32_16x16x32_i8(a.x, b.x, c, 0, 0, 0);
    return __builtin_amdgcn_mfma_i32_16x16x32_i8(a.y, b.y, c, 0, 0, 0);
}
// quad_perm broadcast of quad-lane Q (pure-VALU cross-lane, no LDS pipe)
template<int Q> __device__ __forceinline__ float qbcast(float x) {
    return __int_as_float(__builtin_amdgcn_mov_dpp(
        __float_as_int(x), Q * 0x55, 0xF, 0xF, false));
}

// ---------------- K1a: pre8[ch*512 + (j*4+gt)] = s_e * LOG2E*(b_c[g] + Wih_c[g]·char_emb[ch])
// s_e = -2 for the g-gate (tanh), -1 otherwise: folds the exp2 argument scale in.
__global__ void prep_char(const float* __restrict__ Wih_c, const float* __restrict__ char_emb,
                          const float* __restrict__ bih_c, const float* __restrict__ bhh_c,
                          float* __restrict__ pre8) {
    int ch = blockIdx.x;      // 128
    int g  = threadIdx.x;     // 512
    float acc = bih_c[g] + bhh_c[g];
    const float* w = Wih_c + g * CEMB;
    const float* e = char_emb + ch * CEMB;
#pragma unroll
    for (int k = 0; k < CEMB; k++) acc += w[k] * e[k];
    int gt = g >> 7, j = g & 127;
    float s_e = (gt == 2) ? -2.f : -1.f;
    pre8[((ch * 128) + j) * 4 + gt] = acc * LOG2E * s_e;
}

// ---------------- K1b: per-row i8 quantization of Whh_w. 1024 blocks x 64.
__global__ void prep_wq(const float* __restrict__ Whh_w, signed char* __restrict__ wq,
                        float* __restrict__ sw) {
    int g = blockIdx.x;
    int lane = threadIdx.x;   // 64
    float4 v = reinterpret_cast<const float4*>(Whh_w + (size_t)g * HID)[lane];
    float m = fmaxf(fmaxf(fabsf(v.x), fabsf(v.y)), fmaxf(fabsf(v.z), fabsf(v.w)));
#pragma unroll
    for (int off = 32; off; off >>= 1) m = fmaxf(m, __shfl_xor(m, off, 64));
    m = fmaxf(m, 1e-20f);
    float inv = 127.f / m;
    int q0 = __float2int_rn(v.x * inv), q1 = __float2int_rn(v.y * inv);
    int q2 = __float2int_rn(v.z * inv), q3 = __float2int_rn(v.w * inv);
    int packed = (q0 & 255) | ((q1 & 255) << 8) | ((q2 & 255) << 16) | ((q3 & 255) << 24);
    reinterpret_cast<int*>(wq)[g * 64 + lane] = packed;
    if (lane == 0) sw[g] = m / 127.f;
}

// ---------------- K2: char LSTM, 4-wave dot4 form. 256 blocks x 1 chain, 256 threads.
// TWO GATES PER LANE: lane = 4*jl + nt, wave w handles j = w*16+jl and j+64.
// Each lane reads the 128B h vector ONCE (8 wave-uniform ds_read_b128, broadcast)
// and feeds BOTH its gate rows -> LDS-read pipe traffic halves vs the 8-wave form;
// barrier rendezvous is 4 waves. sdot4 issue per SIMD unchanged (1 wave x 64).
// Integer dot + activation bit-identical to the proven R0 path.
__global__ __launch_bounds__(256, 1) void char_lstm(
        const int* __restrict__ words, const float* __restrict__ Whh_c,
        const float* __restrict__ pre8, float* __restrict__ cf) {
    int t    = blockIdx.x;               // chain
    int tid  = threadIdx.x;              // 0..255
    int lane = tid & 63, w = tid >> 6;   // 4 waves
    int nt   = lane & 3;
    int jl   = lane >> 2;
    int j0   = w * 16 + jl;              // first owned hidden dim (0..63)
    int j1   = j0 + 64;                  // second owned hidden dim (64..127)
    int g0   = nt * 128 + j0;
    int g1   = nt * 128 + j1;

    __shared__ __align__(16) signed char hv[2][128];   // h as i8, dbuf, 256 B

    // ---- per-lane i8 quant of BOTH owned rows (identical rounding to R0)
    int wq0[32], wq1[32];
    float swl0, swl1;
    float s_e = (nt == 2) ? -2.f : -1.f;
    {
        const float4* wr = reinterpret_cast<const float4*>(Whh_c + (size_t)g0 * CHID);
        float mx = 1e-20f;
#pragma unroll
        for (int q = 0; q < 32; q++) {
            float4 f = wr[q];
            mx = fmaxf(mx, fmaxf(fmaxf(fabsf(f.x), fabsf(f.y)), fmaxf(fabsf(f.z), fabsf(f.w))));
        }
        float inv = 127.f / mx;
#pragma unroll
        for (int q = 0; q < 32; q++) {
            float4 f = wr[q];
            wq0[q] = (__float2int_rn(f.x * inv) & 255)
                   | ((__float2int_rn(f.y * inv) & 255) << 8)
                   | ((__float2int_rn(f.z * inv) & 255) << 16)
                   | ((__float2int_rn(f.w * inv) & 255) << 24);
        }
        swl0 = s_e * mx * (LOG2E / (127.f * 127.f));
    }
    {
        const float4* wr = reinterpret_cast<const float4*>(Whh_c + (size_t)g1 * CHID);
        float mx = 1e-20f;
#pragma unroll
        for (int q = 0; q < 32; q++) {
            float4 f = wr[q];
            mx = fmaxf(mx, fmaxf(fmaxf(fabsf(f.x), fabsf(f.y)), fmaxf(fabsf(f.z), fabsf(f.w))));
        }
        float inv = 127.f / mx;
#pragma unroll
        for (int q = 0; q < 32; q++) {
            float4 f = wr[q];
            wq1[q] = (__float2int_rn(f.x * inv) & 255)
                   | ((__float2int_rn(f.y * inv) & 255) << 8)
                   | ((__float2int_rn(f.z * inv) & 255) << 16)
                   | ((__float2int_rn(f.w * inv) & 255) << 24);
        }
        swl1 = s_e * mx * (LOG2E / (127.f * 127.f));
    }
    float m_a = (nt == 2) ?  2.f :  1.f;
    float b_a = (nt == 2) ? -1.f :  0.f;

    if (tid < 64) { reinterpret_cast<int*>(hv)[tid] = 0; }

    float cst0 = 0.f, cst1 = 0.f;        // cell states for j0 and j1
    int cid0 = words[t];
    int cid1 = words[SENT_LEN + t];
    // pre for lane's two gates: offsets tid (gate (j0,nt)) and tid+256 (gate (j1,nt))
    float pa0 = pre8[(size_t)cid0 * 512 + tid];
    float pb0 = pre8[(size_t)cid0 * 512 + 256 + tid];
    float pa1 = pre8[(size_t)cid1 * 512 + tid];
    float pb1 = pre8[(size_t)cid1 * 512 + 256 + tid];
    int ci2 = words[2 * SENT_LEN + t];
    int ci3 = words[3 * SENT_LEN + t];
    __syncthreads();

    for (int u = 0; u < 512; u++) {          // steps 2u (A), 2u+1 (B)
        float fa0 = pre8[(size_t)ci2 * 512 + tid];
        float fb0 = pre8[(size_t)ci2 * 512 + 256 + tid];
        float fa1 = pre8[(size_t)ci3 * 512 + tid];
        float fb1 = pre8[(size_t)ci3 * 512 + 256 + tid];
        ci2 = words[(((u << 1) + 4) & 1023) * SENT_LEN + t];
        ci3 = words[(((u << 1) + 5) & 1023) * SENT_LEN + t];

        {   // step A: read hv[0] -> write hv[1]
            const i32x4* hp = reinterpret_cast<const i32x4*>(hv[0]);
            i32x4 h0 = hp[0], h1 = hp[1], h2 = hp[2], h3 = hp[3];
            i32x4 h4 = hp[4], h5 = hp[5], h6 = hp[6], h7 = hp[7];
            int a0 = 0, a1 = 0, a2 = 0, a3 = 0;
            int b0 = 0, b1 = 0, b2 = 0, b3 = 0;
#define DOT8(hh, base) \
            a0 = __builtin_amdgcn_sdot4(hh.x, wq0[base + 0], a0, false); \
            a1 = __builtin_amdgcn_sdot4(hh.y, wq0[base + 1], a1, false); \
            a2 = __builtin_amdgcn_sdot4(hh.z, wq0[base + 2], a2, false); \
            a3 = __builtin_amdgcn_sdot4(hh.w, wq0[base + 3], a3, false); \
            b0 = __builtin_amdgcn_sdot4(hh.x, wq1[base + 0], b0, false); \
            b1 = __builtin_amdgcn_sdot4(hh.y, wq1[base + 1], b1, false); \
            b2 = __builtin_amdgcn_sdot4(hh.z, wq1[base + 2], b2, false); \
            b3 = __builtin_amdgcn_sdot4(hh.w, wq1[base + 3], b3, false);
            DOT8(h0, 0) DOT8(h1, 4) DOT8(h2, 8) DOT8(h3, 12)
            DOT8(h4, 16) DOT8(h5, 20) DOT8(h6, 24) DOT8(h7, 28)
            int s0 = (a0 + a1) + (a2 + a3);
            int s1 = (b0 + b1) + (b2 + b3);
            float e0  = __builtin_amdgcn_exp2f(fmaf((float)s0, swl0, pa0));
            float av0 = m_a * rcpf(1.f + e0) + b_a;
            float e1  = __builtin_amdgcn_exp2f(fmaf((float)s1, swl1, pb0));
            float av1 = m_a * rcpf(1.f + e1) + b_a;
            float qi0 = qbcast<0>(av0), qf0 = qbcast<1>(av0), qg0 = qbcast<2>(av0), qo0 = qbcast<3>(av0);
            float qi1 = qbcast<0>(av1), qf1 = qbcast<1>(av1), qg1 = qbcast<2>(av1), qo1 = qbcast<3>(av1);
            float cv0 = fmaf(qf0, cst0, qi0 * qg0); cst0 = cv0;
            float cv1 = fmaf(qf1, cst1, qi1 * qg1); cst1 = cv1;
            float tc0 = 2.f * rcpf(1.f + __builtin_amdgcn_exp2f(N2LOG2E * cv0)) - 1.f;
            float tc1 = 2.f * rcpf(1.f + __builtin_amdgcn_exp2f(N2LOG2E * cv1)) - 1.f;
            float hh0 = qo0 * tc0;
            float hh1 = qo1 * tc1;
            if (nt == 0) {
                hv[1][j0] = (signed char)__float2int_rn(hh0 * 127.f);
                hv[1][j1] = (signed char)__float2int_rn(hh1 * 127.f);
            }
            block_sync_lds();
            pa0 = pa1; pb0 = pb1;       // shift prefetch pipeline
            pa1 = fa0; pb1 = fb0;
            // step B uses (pa0,pb0); new (pa1,pb1) hold step m+2... fixed below
            // NOTE: we keep the same 2-ahead discipline as R0: A consumes (pa0,pb0)
            // which entered two halves ago.
            (void)fa1; (void)fb1;
            // reassign for clarity at loop end (see below)
            pa1 = pa1; // no-op
            // stash step-(2u+3) values for the end-of-loop shift:
            // handled after step B.
            // (fa1, fb1) consumed after step B.
            // fallthrough
            // ---- step B below
            {   // step B: read hv[1] -> write hv[0]
                const i32x4* hq = reinterpret_cast<const i32x4*>(hv[1]);
                i32x4 g0v = hq[0], g1v = hq[1], g2v = hq[2], g3v = hq[3];
                i32x4 g4v = hq[4], g5v = hq[5], g6v = hq[6], g7v = hq[7];
                int c0 = 0, c1 = 0, c2 = 0, c3 = 0;
                int d0 = 0, d1 = 0, d2 = 0, d3 = 0;
#define DOT8B(hh, base) \
                c0 = __builtin_amdgcn_sdot4(hh.x, wq0[base + 0], c0, false); \
                c1 = __builtin_amdgcn_sdot4(hh.y, wq0[base + 1], c1, false); \
                c2 = __builtin_amdgcn_sdot4(hh.z, wq0[base + 2], c2, false); \
                c3 = __builtin_amdgcn_sdot4(hh.w, wq0[base + 3], c3, false); \
                d0 = __builtin_amdgcn_sdot4(hh.x, wq1[base + 0], d0, false); \
                d1 = __builtin_amdgcn_sdot4(hh.y, wq1[base + 1], d1, false); \
                d2 = __builtin_amdgcn_sdot4(hh.z, wq1[base + 2], d2, false); \
                d3 = __builtin_amdgcn_sdot4(hh.w, wq1[base + 3], d3, false);
                DOT8B(g0v, 0) DOT8B(g1v, 4) DOT8B(g2v, 8) DOT8B(g3v, 12)
                DOT8B(g4v, 16) DOT8B(g5v, 20) DOT8B(g6v, 24) DOT8B(g7v, 28)
                int t0s = (c0 + c1) + (c2 + c3);
                int t1s = (d0 + d1) + (d2 + d3);
                float e0b  = __builtin_amdgcn_exp2f(fmaf((float)t0s, swl0, pa0));
                float av0b = m_a * rcpf(1.f + e0b) + b_a;
                float e1b  = __builtin_amdgcn_exp2f(fmaf((float)t1s, swl1, pb0));
                float av1b = m_a * rcpf(1.f + e1b) + b_a;
                float qi0b = qbcast<0>(av0b), qf0b = qbcast<1>(av0b), qg0b = qbcast<2>(av0b), qo0b = qbcast<3>(av0b);
                float qi1b = qbcast<0>(av1b), qf1b = qbcast<1>(av1b), qg1b = qbcast<2>(av1b), qo1b = qbcast<3>(av1b);
                float cv0b = fmaf(qf0b, cst0, qi0b * qg0b); cst0 = cv0b;
                float cv1b = fmaf(qf1b, cst1, qi1b * qg1b); cst1 = cv1b;
                float tc0b = 2.f * rcpf(1.f + __builtin_amdgcn_exp2f(N2LOG2E * cv0b)) - 1.f;
                float tc1b = 2.f * rcpf(1.f + __builtin_amdgcn_exp2f(N2LOG2E * cv1b)) - 1.f;
                float hb0 = qo0b * tc0b;
                float hb1 = qo1b * tc1b;
                if (nt == 0) {
                    hv[0][j0] = (signed char)__float2int_rn(hb0 * 127.f);
                    hv[0][j1] = (signed char)__float2int_rn(hb1 * 127.f);
                    if ((u & 7) == 7) {
                        cf[((size_t)t * SENT_BATCH + (u >> 3)) * CHID + j0] = hb0;
                        cf[((size_t)t * SENT_BATCH + (u >> 3)) * CHID + j1] = hb1;
                    }
                }
                block_sync_lds();
            }
            // shift: B consumed (pa0,pb0); next A consumes old (pa1,pb1)=fa0-era...
            pa0 = pa1; pb0 = pb1;       // now hold step 2u+2's pre (fa0,fb0)
            pa1 = fa1; pb1 = fb1;       // step 2u+3's pre
        }
    }
}

// ---------------- K3: bf16 MFMA GEMM (R12 form). xw8[(b*256+t)*256+j] = uint2{bf16 gates}.
#define XW_SEG 65   // 16B units per LDS segment (64 lanes + 1 pad)
__global__ __launch_bounds__(256, 2) void xw_gemm(
        const int* __restrict__ sentences, const float* __restrict__ word_emb,
        const float* __restrict__ cf, const float* __restrict__ Wih_w,
        const float* __restrict__ bih_w, const float* __restrict__ bhh_w,
        uint2* __restrict__ xw8) {
    __shared__ short8 Apack[32 * XW_SEG];   // segment s = kt*4 + wv(m-tile)
    __shared__ short8 Bpack[32 * XW_SEG];   // segment s = kt*4 + nt(gate type)
    __shared__ int sid_s[64];
    int tid = threadIdx.x;
    int j0 = blockIdx.x * 16;
    int row0 = blockIdx.y * 64;             // row0 = t*64: whole block is one t
    if (tid < 64) sid_s[tid] = sentences[row0 + tid];
    __syncthreads();

#pragma unroll
    for (int it = 0; it < 8; it++) {
        int idx = it * 256 + tid;
        int m = idx >> 5, k8 = idx & 31;
        int k = k8 * 8;
        int kt = k8 >> 2, lqs = k8 & 3;
        int lanes = (m & 15) + (lqs << 4);
        int seg = kt * 4 + (m >> 4);
        const float* asrc = (k < EMB)
            ? word_emb + (size_t)sid_s[m] * EMB + k
            : cf + (size_t)(row0 + m) * CHID + (k - EMB);
        float4 a0 = reinterpret_cast<const float4*>(asrc)[0];
        float4 a1 = reinterpret_cast<const float4*>(asrc)[1];
        short8 av;
        av[0] = (short)f2bfu(a0.x); av[1] = (short)f2bfu(a0.y);
        av[2] = (short)f2bfu(a0.z); av[3] = (short)f2bfu(a0.w);
        av[4] = (short)f2bfu(a1.x); av[5] = (short)f2bfu(a1.y);
        av[6] = (short)f2bfu(a1.z); av[7] = (short)f2bfu(a1.w);
        Apack[seg * XW_SEG + lanes] = av;
        const float* bsrc = Wih_w + (size_t)((m >> 4) * 256 + j0 + (m & 15)) * K_IN + k;
        float4 b0 = reinterpret_cast<const float4*>(bsrc)[0];
        float4 b1 = reinterpret_cast<const float4*>(bsrc)[1];
        short8 bv;
        bv[0] = (short)f2bfu(b0.x); bv[1] = (short)f2bfu(b0.y);
        bv[2] = (short)f2bfu(b0.z); bv[3] = (short)f2bfu(b0.w);
        bv[4] = (short)f2bfu(b1.x); bv[5] = (short)f2bfu(b1.y);
        bv[6] = (short)f2bfu(b1.z); bv[7] = (short)f2bfu(b1.w);
        Bpack[seg * XW_SEG + lanes] = bv;
    }
    __syncthreads();

    int lane = tid & 63, wv = tid >> 6, l15 = lane & 15, lq = lane >> 4;
    f32x4 acc[4] = {{0.f,0.f,0.f,0.f},{0.f,0.f,0.f,0.f},{0.f,0.f,0.f,0.f},{0.f,0.f,0.f,0.f}};
#pragma unroll
    for (int kt = 0; kt < 8; kt++) {
        short8 a = Apack[(kt * 4 + wv) * XW_SEG + lane];
#pragma unroll
        for (int nt = 0; nt < 4; nt++)
            acc[nt] = __builtin_amdgcn_mfma_f32_16x16x32_bf16(
                a, Bpack[(kt * 4 + nt) * XW_SEG + lane], acc[nt], 0, 0, 0);
    }
    float bb[4];
#pragma unroll
    for (int nt = 0; nt < 4; nt++)
        bb[nt] = bih_w[nt * 256 + j0 + l15] + bhh_w[nt * 256 + j0 + l15];
    int t = row0 >> 6;
#pragma unroll
    for (int r = 0; r < 4; r++) {
        int b = wv * 16 + lq * 4 + r;       // chain index within this t
        uint2 o;
        o.x = (unsigned)f2bfu((acc[0][r] + bb[0]) * LOG2E)
            | ((unsigned)f2bfu((acc[1][r] + bb[1]) * LOG2E) << 16);
        o.y = (unsigned)f2bfu((acc[2][r] + bb[2]) * LOG2E)
            | ((unsigned)f2bfu((acc[3][r] + bb[3]) * LOG2E) << 16);
        xw8[((size_t)b * SENT_LEN + t) * 256 + j0 + l15] = o;
    }
}

// ---------------- K4: word LSTM. 64 blocks x 1 chain, 1024 threads (16 waves).
__global__ __launch_bounds__(1024, 1) void word_lstm(
        const uint2* __restrict__ xw8, const signed char* __restrict__ wq,
        const float* __restrict__ sw, float* __restrict__ h_out) {
    int b    = blockIdx.x;               // chain 0..63
    int tid  = threadIdx.x;
    int lane = tid & 63, w = tid >> 6;   // 16 waves
    int l15  = lane & 15, lq = lane >> 4;
    int j    = w * 16 + l15;

    __shared__ __align__(16) signed char hv[2][256];   // h as i8, dbuf, 512 B

    lng2 bfr[4][4];
    float swl[4];
#pragma unroll
    for (int nt = 0; nt < 4; nt++) {
        int g = nt * 256 + j;
        swl[nt] = sw[g] * (LOG2E / 127.f);
#pragma unroll
        for (int kt = 0; kt < 4; kt++)
            bfr[nt][kt] = reinterpret_cast<const lng2*>(wq + (size_t)g * HID + kt * 64 + lq * 16)[0];
    }
    if (tid < 128) { reinterpret_cast<int*>(hv)[tid] = 0; }

    const uint2* xwb = xw8 + (size_t)b * SENT_LEN * 256;   // this block's stream
    float cst = 0.f;
    uint2 xq0 = xwb[0 * 256 + j];
    uint2 xq1 = xwb[1 * 256 + j];
    uint2 xq2 = xwb[2 * 256 + j];
    uint2 xq3 = xwb[3 * 256 + j];
    __syncthreads();

    for (int u = 0; u < 128; u++) {          // steps 2u (A), 2u+1 (B)
        uint2 xn0 = xwb[((((u << 1) + 4) & 255)) * 256 + j];
        uint2 xn1 = xwb[((((u << 1) + 5) & 255)) * 256 + j];

        {   // step A: read hv[0] -> write hv[1]
            const lng2* hp = reinterpret_cast<const lng2*>(hv[0]);
            i32x4 acc[4] = {};
#pragma unroll
            for (int kt = 0; kt < 4; kt++) {
                lng2 a = hp[kt * 4 + lq];
#pragma unroll
                for (int nt = 0; nt < 4; nt++)
                    acc[nt] = mfma_i8_k64(a, bfr[nt][kt], acc[nt]);
            }
            float gi = (float)acc[0][0] * swl[0] + bf_lo(xq0.x);
            float gf = (float)acc[1][0] * swl[1] + bf_hi(xq0.x);
            float gg = (float)acc[2][0] * swl[2] + bf_lo(xq0.y);
            float go = (float)acc[3][0] * swl[3] + bf_hi(xq0.y);
            float h = lstm_act(gi, gf, gg, go, cst);
            if (lq == 0) {
                h_out[((size_t)(u << 1) * SENT_BATCH + b) * HID + j] = h;
                hv[1][j] = (signed char)__float2int_rn(h * 127.f);
            }
            block_sync_lds();
        }
        {   // step B: read hv[1] -> write hv[0]
            const lng2* hp = reinterpret_cast<const lng2*>(hv[1]);
            i32x4 acc[4] = {};
#pragma unroll
            for (int kt = 0; kt < 4; kt++) {
                lng2 a = hp[kt * 4 + lq];
#pragma unroll
                for (int nt = 0; nt < 4; nt++)
                    acc[nt] = mfma_i8_k64(a, bfr[nt][kt], acc[nt]);
            }
            float gi = (float)acc[0][0] * swl[0] + bf_lo(xq1.x);
            float gf = (float)acc[1][0] * swl[1] + bf_hi(xq1.x);
            float gg = (float)acc[2][0] * swl[2] + bf_lo(xq1.y);
            float go = (float)acc[3][0] * swl[3] + bf_hi(xq1.y);
            float h = lstm_act(gi, gf, gg, go, cst);
            if (lq == 0) {
                h_out[((size_t)((u << 1) + 1) * SENT_BATCH + b) * HID + j] = h;
                hv[0][j] = (signed char)__float2int_rn(h * 127.f);
            }
            block_sync_lds();
        }
        xq0 = xq2; xq1 = xq3; xq2 = xn0; xq3 = xn1;
    }
}

// ---------------- K5: tag projection + log_softmax. 8 rows/block (W_tag staging amortized).
__global__ __launch_bounds__(256) void tag_logsoftmax(
        const float* __restrict__ h_out, const float* __restrict__ W_tag,
        const float* __restrict__ b_tag, float* __restrict__ out) {
    __shared__ float wt_s[TAGS * 257];      // 51.4 KB
    __shared__ float hr_s[8 * HID];         // 8 KB
    int tid = threadIdx.x;
    int row0 = blockIdx.x * 8;
#pragma unroll 2
    for (int i = 0; i < TAGS; i++) wt_s[i * 257 + tid] = W_tag[i * HID + tid];
#pragma unroll
    for (int w = 0; w < 8; w++) hr_s[w * HID + tid] = h_out[(size_t)(row0 + w) * HID + tid];
    __syncthreads();

    int w4 = tid >> 6, l = tid & 63;
#pragma unroll
    for (int rep = 0; rep < 2; rep++) {
        int w = rep * 4 + w4;
        float acc = 0.f;
        if (l < TAGS) {
            acc = b_tag[l];
            const float* hr = hr_s + w * HID;
            const float* wr = wt_s + l * 257;
#pragma unroll 4
            for (int k = 0; k < HID; k++) acc += hr[k] * wr[k];
        }
        float m = (l < TAGS) ? acc : -1e30f;
#pragma unroll
        for (int off = 32; off; off >>= 1) m = fmaxf(m, __shfl_xor(m, off, 64));
        float e = (l < TAGS) ? __builtin_amdgcn_exp2f((acc - m) * LOG2E) : 0.f;
        float ssum = e;
#pragma unroll
        for (int off = 32; off; off >>= 1) ssum += __shfl_xor(ssum, off, 64);
        float lse = m + __logf(ssum);
        if (l < TAGS) out[(size_t)(row0 + w) * TAGS + l] = acc - lse;
    }
}

extern "C" void kernel_launch(void* const* d_in, const int* in_sizes, int n_in,
                              void* d_out, int out_size, void* d_ws, size_t ws_size,
                              hipStream_t stream) {
    (void)in_sizes; (void)n_in; (void)out_size; (void)ws_size;
    const int*   sentences = (const int*)d_in[0];
    const int*   words     = (const int*)d_in[1];
    const float* word_emb  = (const float*)d_in[4];
    const float* char_emb  = (const float*)d_in[5];
    const float* Wih_c     = (const float*)d_in[6];
    const float* Whh_c     = (const float*)d_in[7];
    const float* bih_c     = (const float*)d_in[8];
    const float* bhh_c     = (const float*)d_in[9];
    const float* Wih_w     = (const float*)d_in[10];
    const float* Whh_w     = (const float*)d_in[11];
    const float* bih_w     = (const float*)d_in[12];
    const float* bhh_w     = (const float*)d_in[13];
    const float* W_tag     = (const float*)d_in[14];
    const float* b_tag     = (const float*)d_in[15];
    float* out = (float*)d_out;

    char* ws = (char*)d_ws;
    size_t off = 0;
    float* pre8 = (float*)(ws + off);                 off += 128 * 512 * sizeof(float);      // 256 KB
    signed char* wq = (signed char*)(ws + off);       off += 1024 * 256;                     // 256 KB
    float* sw = (float*)(ws + off);                   off += 1024 * sizeof(float);           // 4 KB
    off = (off + 255) & ~(size_t)255;
    float* cf = (float*)(ws + off);                   off += (size_t)SENT_LEN * SENT_BATCH * CHID * sizeof(float); // 8.4 MB
    uint2* xw8 = (uint2*)(ws + off);                  off += (size_t)SENT_LEN * SENT_BATCH * 256 * sizeof(uint2);  // 33.5 MB
    float* h_out = (float*)(ws + off);                off += (size_t)SENT_LEN * SENT_BATCH * HID * sizeof(float);  // 16.8 MB

    hipLaunchKernelGGL(prep_char, dim3(128), dim3(512), 0, stream,
                       Wih_c, char_emb, bih_c, bhh_c, pre8);
    hipLaunchKernelGGL(prep_wq, dim3(1024), dim3(64), 0, stream, Whh_w, wq, sw);
    hipLaunchKernelGGL(char_lstm, dim3(256), dim3(256), 0, stream,
                       words, Whh_c, pre8, cf);
    hipLaunchKernelGGL(xw_gemm, dim3(16, 256), dim3(256), 0, stream,
                       sentences, word_emb, cf, Wih_w, bih_w, bhh_w, xw8);
    hipLaunchKernelGGL(word_lstm, dim3(SENT_BATCH), dim3(1024), 0, stream,
                       xw8, wq, sw, h_out);
    hipLaunchKernelGGL(tag_logsoftmax, dim3((SENT_LEN * SENT_BATCH) / 8), dim3(256), 0, stream,
                       h_out, W_tag, b_tag, out);
}

// Round 7
// 955.141 us; speedup vs baseline: 1.1426x; 1.0621x over previous
//
#include <hip/hip_runtime.h>
#include <hip/hip_bf16.h>
#include <cstdint>

#define SENT_LEN   256
#define SENT_BATCH 64
#define WORD_LEN   16
#define EMB        128
#define HID        256
#define CEMB       64
#define CHID       128
#define TAGS       50
#define K_IN       (EMB + CHID)   // 256
#define LOG2E      1.44269504f
#define N2LOG2E    -2.88539008f   // -2*log2(e)

typedef __attribute__((ext_vector_type(8))) short short8;
typedef __attribute__((ext_vector_type(4))) float f32x4;
typedef __attribute__((ext_vector_type(4))) int   i32x4;
typedef __attribute__((ext_vector_type(2))) long  lng2;

__device__ __forceinline__ float rcpf(float x) { return __builtin_amdgcn_rcpf(x); }
// inputs pre-scaled by log2e: sig2(xl) = sigmoid(xl/log2e)
__device__ __forceinline__ float sig2(float xl) {
    return rcpf(1.f + __builtin_amdgcn_exp2f(-xl));
}
// tanh via sigmoid identity, clamp-free: tanh(x) = 2*sigmoid(2x)-1.
__device__ __forceinline__ float tanh2(float xl) {
    float e = __builtin_amdgcn_exp2f(-(xl + xl));
    return 2.f * rcpf(1.f + e) - 1.f;
}
__device__ __forceinline__ float lstm_act(float gi, float gf, float gg, float go, float& cst) {
    float c = sig2(gf) * cst + sig2(gi) * tanh2(gg);
    cst = c;
    float tc = 2.f * rcpf(1.f + __builtin_amdgcn_exp2f(N2LOG2E * c)) - 1.f;
    return sig2(go) * tc;
}
__device__ __forceinline__ float bf_lo(unsigned u) { return __uint_as_float(u << 16); }
__device__ __forceinline__ float bf_hi(unsigned u) { return __uint_as_float(u & 0xffff0000u); }
// branch-free RNE bf16 (finite inputs only)
__device__ __forceinline__ unsigned short f2bfu(float f) {
    unsigned u = __float_as_uint(f);
    u += 0x7fff + ((u >> 16) & 1);
    return (unsigned short)(u >> 16);
}
// CK-style barrier: drains LDS (lgkmcnt) only — global prefetches stay in flight.
__device__ __forceinline__ void block_sync_lds() {
    asm volatile("s_waitcnt lgkmcnt(0)\ns_barrier" ::: "memory");
}
// 16-byte K-fragment MFMA as two K=32 i8 calls (word_lstm path).
__device__ __forceinline__ i32x4 mfma_i8_k64(lng2 a, lng2 b, i32x4 c) {
    c = __builtin_amdgcn_mfma_i32_16x16x32_i8(a.x, b.x, c, 0, 0, 0);
    return __builtin_amdgcn_mfma_i32_16x16x32_i8(a.y, b.y, c, 0, 0, 0);
}
// quad_perm broadcast of quad-lane Q (pure-VALU cross-lane, no LDS pipe)
template<int Q> __device__ __forceinline__ float qbcast(float x) {
    return __int_as_float(__builtin_amdgcn_mov_dpp(
        __float_as_int(x), Q * 0x55, 0xF, 0xF, false));
}

// ---------------- K1a: pre8[ch*512 + (j*4+gt)] = s_e * LOG2E*(b_c[g] + Wih_c[g]·char_emb[ch])
// s_e = -2 for the g-gate (tanh), -1 otherwise: folds the exp2 argument scale in.
__global__ void prep_char(const float* __restrict__ Wih_c, const float* __restrict__ char_emb,
                          const float* __restrict__ bih_c, const float* __restrict__ bhh_c,
                          float* __restrict__ pre8) {
    int ch = blockIdx.x;      // 128
    int g  = threadIdx.x;     // 512
    float acc = bih_c[g] + bhh_c[g];
    const float* w = Wih_c + g * CEMB;
    const float* e = char_emb + ch * CEMB;
#pragma unroll
    for (int k = 0; k < CEMB; k++) acc += w[k] * e[k];
    int gt = g >> 7, j = g & 127;
    float s_e = (gt == 2) ? -2.f : -1.f;
    pre8[((ch * 128) + j) * 4 + gt] = acc * LOG2E * s_e;
}

// ---------------- K1b: per-row i8 quantization of Whh_w + bf16 copy of Wih_w row.
// 1024 blocks x 64.
__global__ void prep_wq(const float* __restrict__ Whh_w, const float* __restrict__ Wih_w,
                        signed char* __restrict__ wq, float* __restrict__ sw,
                        unsigned short* __restrict__ wihb) {
    int g = blockIdx.x;
    int lane = threadIdx.x;   // 64
    float4 v = reinterpret_cast<const float4*>(Whh_w + (size_t)g * HID)[lane];
    float m = fmaxf(fmaxf(fabsf(v.x), fabsf(v.y)), fmaxf(fabsf(v.z), fabsf(v.w)));
#pragma unroll
    for (int off = 32; off; off >>= 1) m = fmaxf(m, __shfl_xor(m, off, 64));
    m = fmaxf(m, 1e-20f);
    float inv = 127.f / m;
    int q0 = __float2int_rn(v.x * inv), q1 = __float2int_rn(v.y * inv);
    int q2 = __float2int_rn(v.z * inv), q3 = __float2int_rn(v.w * inv);
    int packed = (q0 & 255) | ((q1 & 255) << 8) | ((q2 & 255) << 16) | ((q3 & 255) << 24);
    reinterpret_cast<int*>(wq)[g * 64 + lane] = packed;
    if (lane == 0) sw[g] = m / 127.f;
    // bf16 copy of Wih_w row g (xw_gemm B operand): bit-identical to per-block f2bfu
    float4 wv = reinterpret_cast<const float4*>(Wih_w + (size_t)g * K_IN)[lane];
    uint2 p;
    p.x = (unsigned)f2bfu(wv.x) | ((unsigned)f2bfu(wv.y) << 16);
    p.y = (unsigned)f2bfu(wv.z) | ((unsigned)f2bfu(wv.w) << 16);
    reinterpret_cast<uint2*>(wihb + (size_t)g * K_IN)[lane] = p;
}

// ---------------- K2: char LSTM, dot4 form (proven R0 structure, folded constants).
// 256 blocks x 1 chain, 512 threads (8 waves = 2/SIMD: TLP hides ds_read + epilogue).
// ONE GATE PER LANE: lane = 4*j_local + nt. h as i8 in LDS (128 B, dbuf); weights
// VGPR-resident (32 dwords); 32 v_dot4_i32_i8 per lane per step.
__global__ __launch_bounds__(512, 1) void char_lstm(
        const int* __restrict__ words, const float* __restrict__ Whh_c,
        const float* __restrict__ pre8, float* __restrict__ cf) {
    int t    = blockIdx.x;               // chain
    int tid  = threadIdx.x;
    int lane = tid & 63, w = tid >> 6;   // 8 waves
    int nt   = lane & 3;
    int j    = w * 16 + (lane >> 2);
    int g    = nt * 128 + j;             // this lane's gate row

    __shared__ __align__(16) signed char hv[2][128];   // h as i8, dbuf, 256 B

    // ---- per-lane i8 quant of this lane's Whh_c row
    const float4* wr = reinterpret_cast<const float4*>(Whh_c + (size_t)g * CHID);
    float mx = 1e-20f;
#pragma unroll
    for (int q = 0; q < 32; q++) {
        float4 f = wr[q];
        mx = fmaxf(mx, fmaxf(fmaxf(fabsf(f.x), fabsf(f.y)), fmaxf(fabsf(f.z), fabsf(f.w))));
    }
    float inv = 127.f / mx;
    int wqr[32];
#pragma unroll
    for (int q = 0; q < 32; q++) {
        float4 f = wr[q];
        wqr[q] = (__float2int_rn(f.x * inv) & 255)
               | ((__float2int_rn(f.y * inv) & 255) << 8)
               | ((__float2int_rn(f.z * inv) & 255) << 16)
               | ((__float2int_rn(f.w * inv) & 255) << 24);
    }
    float s_e   = (nt == 2) ? -2.f : -1.f;
    float swl_s = s_e * mx * (LOG2E / (127.f * 127.f));
    float m_a   = (nt == 2) ?  2.f :  1.f;
    float b_a   = (nt == 2) ? -1.f :  0.f;

    if (tid < 64) { reinterpret_cast<int*>(hv)[tid] = 0; }

    float cst = 0.f;
    int cid0 = words[t];
    int cid1 = words[SENT_LEN + t];
    float pl0 = pre8[(size_t)cid0 * 512 + tid];   // this lane's gate pre-input (folded)
    float pl1 = pre8[(size_t)cid1 * 512 + tid];
    int ci2 = words[2 * SENT_LEN + t];
    int ci3 = words[3 * SENT_LEN + t];
    __syncthreads();

    for (int u = 0; u < 512; u++) {          // steps 2u (A), 2u+1 (B)
        float pf0 = pre8[(size_t)ci2 * 512 + tid];
        float pf1 = pre8[(size_t)ci3 * 512 + tid];
        ci2 = words[(((u << 1) + 4) & 1023) * SENT_LEN + t];
        ci3 = words[(((u << 1) + 5) & 1023) * SENT_LEN + t];

        {   // step A: read hv[0] -> write hv[1]
            const i32x4* hp = reinterpret_cast<const i32x4*>(hv[0]);
            int a0 = 0, a1 = 0, a2 = 0, a3 = 0;
#pragma unroll
            for (int q = 0; q < 8; q++) {
                i32x4 hq = hp[q];
                a0 = __builtin_amdgcn_sdot4(hq.x, wqr[q * 4 + 0], a0, false);
                a1 = __builtin_amdgcn_sdot4(hq.y, wqr[q * 4 + 1], a1, false);
                a2 = __builtin_amdgcn_sdot4(hq.z, wqr[q * 4 + 2], a2, false);
                a3 = __builtin_amdgcn_sdot4(hq.w, wqr[q * 4 + 3], a3, false);
            }
            int s = (a0 + a1) + (a2 + a3);
            float e  = __builtin_amdgcn_exp2f(fmaf((float)s, swl_s, pl0));
            float av = m_a * rcpf(1.f + e) + b_a;     // own gate's nonlinearity
            float qi = qbcast<0>(av);                 // sig(i)
            float qf = qbcast<1>(av);                 // sig(f)
            float qg = qbcast<2>(av);                 // tanh(g)
            float qo = qbcast<3>(av);                 // sig(o)
            float c  = fmaf(qf, cst, qi * qg);
            cst = c;
            float tc = 2.f * rcpf(1.f + __builtin_amdgcn_exp2f(N2LOG2E * c)) - 1.f;
            float h  = qo * tc;
            if (nt == 0)
                hv[1][j] = (signed char)__float2int_rn(h * 127.f);
            block_sync_lds();
        }
        {   // step B: read hv[1] -> write hv[0]
            const i32x4* hp = reinterpret_cast<const i32x4*>(hv[1]);
            int a0 = 0, a1 = 0, a2 = 0, a3 = 0;
#pragma unroll
            for (int q = 0; q < 8; q++) {
                i32x4 hq = hp[q];
                a0 = __builtin_amdgcn_sdot4(hq.x, wqr[q * 4 + 0], a0, false);
                a1 = __builtin_amdgcn_sdot4(hq.y, wqr[q * 4 + 1], a1, false);
                a2 = __builtin_amdgcn_sdot4(hq.z, wqr[q * 4 + 2], a2, false);
                a3 = __builtin_amdgcn_sdot4(hq.w, wqr[q * 4 + 3], a3, false);
            }
            int s = (a0 + a1) + (a2 + a3);
            float e  = __builtin_amdgcn_exp2f(fmaf((float)s, swl_s, pl1));
            float av = m_a * rcpf(1.f + e) + b_a;
            float qi = qbcast<0>(av);
            float qf = qbcast<1>(av);
            float qg = qbcast<2>(av);
            float qo = qbcast<3>(av);
            float c  = fmaf(qf, cst, qi * qg);
            cst = c;
            float tc = 2.f * rcpf(1.f + __builtin_amdgcn_exp2f(N2LOG2E * c)) - 1.f;
            float h  = qo * tc;
            if (nt == 0) {
                hv[0][j] = (signed char)__float2int_rn(h * 127.f);
                if ((u & 7) == 7)
                    cf[((size_t)t * SENT_BATCH + (u >> 3)) * CHID + j] = h;
            }
            block_sync_lds();
        }
        pl0 = pf0; pl1 = pf1;
    }
}

// ---------------- K3: bf16 MFMA GEMM. B from pre-converted wihb (no per-block f2bfu).
#define XW_SEG 65   // 16B units per LDS segment (64 lanes + 1 pad)
__global__ __launch_bounds__(256, 2) void xw_gemm(
        const int* __restrict__ sentences, const float* __restrict__ word_emb,
        const float* __restrict__ cf, const unsigned short* __restrict__ wihb,
        const float* __restrict__ bih_w, const float* __restrict__ bhh_w,
        uint2* __restrict__ xw8) {
    __shared__ short8 Apack[32 * XW_SEG];   // segment s = kt*4 + wv(m-tile)
    __shared__ short8 Bpack[32 * XW_SEG];   // segment s = kt*4 + nt(gate type)
    __shared__ int sid_s[64];
    int tid = threadIdx.x;
    int j0 = blockIdx.x * 16;
    int row0 = blockIdx.y * 64;             // row0 = t*64: whole block is one t
    if (tid < 64) sid_s[tid] = sentences[row0 + tid];
    __syncthreads();

#pragma unroll
    for (int it = 0; it < 8; it++) {
        int idx = it * 256 + tid;
        int m = idx >> 5, k8 = idx & 31;
        int k = k8 * 8;
        int kt = k8 >> 2, lqs = k8 & 3;
        int lanes = (m & 15) + (lqs << 4);
        int seg = kt * 4 + (m >> 4);
        const float* asrc = (k < EMB)
            ? word_emb + (size_t)sid_s[m] * EMB + k
            : cf + (size_t)(row0 + m) * CHID + (k - EMB);
        float4 a0 = reinterpret_cast<const float4*>(asrc)[0];
        float4 a1 = reinterpret_cast<const float4*>(asrc)[1];
        short8 av;
        av[0] = (short)f2bfu(a0.x); av[1] = (short)f2bfu(a0.y);
        av[2] = (short)f2bfu(a0.z); av[3] = (short)f2bfu(a0.w);
        av[4] = (short)f2bfu(a1.x); av[5] = (short)f2bfu(a1.y);
        av[6] = (short)f2bfu(a1.z); av[7] = (short)f2bfu(a1.w);
        Apack[seg * XW_SEG + lanes] = av;
        const unsigned short* bsrc =
            wihb + (size_t)((m >> 4) * 256 + j0 + (m & 15)) * K_IN + k;
        Bpack[seg * XW_SEG + lanes] = *reinterpret_cast<const short8*>(bsrc);
    }
    __syncthreads();

    int lane = tid & 63, wv = tid >> 6, l15 = lane & 15, lq = lane >> 4;
    f32x4 acc[4] = {{0.f,0.f,0.f,0.f},{0.f,0.f,0.f,0.f},{0.f,0.f,0.f,0.f},{0.f,0.f,0.f,0.f}};
#pragma unroll
    for (int kt = 0; kt < 8; kt++) {
        short8 a = Apack[(kt * 4 + wv) * XW_SEG + lane];
#pragma unroll
        for (int nt = 0; nt < 4; nt++)
            acc[nt] = __builtin_amdgcn_mfma_f32_16x16x32_bf16(
                a, Bpack[(kt * 4 + nt) * XW_SEG + lane], acc[nt], 0, 0, 0);
    }
    float bb[4];
#pragma unroll
    for (int nt = 0; nt < 4; nt++)
        bb[nt] = bih_w[nt * 256 + j0 + l15] + bhh_w[nt * 256 + j0 + l15];
    int t = row0 >> 6;
#pragma unroll
    for (int r = 0; r < 4; r++) {
        int b = wv * 16 + lq * 4 + r;       // chain index within this t
        uint2 o;
        o.x = (unsigned)f2bfu((acc[0][r] + bb[0]) * LOG2E)
            | ((unsigned)f2bfu((acc[1][r] + bb[1]) * LOG2E) << 16);
        o.y = (unsigned)f2bfu((acc[2][r] + bb[2]) * LOG2E)
            | ((unsigned)f2bfu((acc[3][r] + bb[3]) * LOG2E) << 16);
        xw8[((size_t)b * SENT_LEN + t) * 256 + j0 + l15] = o;
    }
}

// ---------------- K4: word LSTM. 64 blocks x 1 chain, 1024 threads (16 waves).
__global__ __launch_bounds__(1024, 1) void word_lstm(
        const uint2* __restrict__ xw8, const signed char* __restrict__ wq,
        const float* __restrict__ sw, float* __restrict__ h_out) {
    int b    = blockIdx.x;               // chain 0..63
    int tid  = threadIdx.x;
    int lane = tid & 63, w = tid >> 6;   // 16 waves
    int l15  = lane & 15, lq = lane >> 4;
    int j    = w * 16 + l15;

    __shared__ __align__(16) signed char hv[2][256];   // h as i8, dbuf, 512 B

    lng2 bfr[4][4];
    float swl[4];
#pragma unroll
    for (int nt = 0; nt < 4; nt++) {
        int g = nt * 256 + j;
        swl[nt] = sw[g] * (LOG2E / 127.f);
#pragma unroll
        for (int kt = 0; kt < 4; kt++)
            bfr[nt][kt] = reinterpret_cast<const lng2*>(wq + (size_t)g * HID + kt * 64 + lq * 16)[0];
    }
    if (tid < 128) { reinterpret_cast<int*>(hv)[tid] = 0; }

    const uint2* xwb = xw8 + (size_t)b * SENT_LEN * 256;   // this block's stream
    float cst = 0.f;
    uint2 xq0 = xwb[0 * 256 + j];
    uint2 xq1 = xwb[1 * 256 + j];
    uint2 xq2 = xwb[2 * 256 + j];
    uint2 xq3 = xwb[3 * 256 + j];
    __syncthreads();

    for (int u = 0; u < 128; u++) {          // steps 2u (A), 2u+1 (B)
        uint2 xn0 = xwb[((((u << 1) + 4) & 255)) * 256 + j];
        uint2 xn1 = xwb[((((u << 1) + 5) & 255)) * 256 + j];

        {   // step A: read hv[0] -> write hv[1]
            const lng2* hp = reinterpret_cast<const lng2*>(hv[0]);
            i32x4 acc[4] = {};
#pragma unroll
            for (int kt = 0; kt < 4; kt++) {
                lng2 a = hp[kt * 4 + lq];
#pragma unroll
                for (int nt = 0; nt < 4; nt++)
                    acc[nt] = mfma_i8_k64(a, bfr[nt][kt], acc[nt]);
            }
            float gi = (float)acc[0][0] * swl[0] + bf_lo(xq0.x);
            float gf = (float)acc[1][0] * swl[1] + bf_hi(xq0.x);
            float gg = (float)acc[2][0] * swl[2] + bf_lo(xq0.y);
            float go = (float)acc[3][0] * swl[3] + bf_hi(xq0.y);
            float h = lstm_act(gi, gf, gg, go, cst);
            if (lq == 0) {
                h_out[((size_t)(u << 1) * SENT_BATCH + b) * HID + j] = h;
                hv[1][j] = (signed char)__float2int_rn(h * 127.f);
            }
            block_sync_lds();
        }
        {   // step B: read hv[1] -> write hv[0]
            const lng2* hp = reinterpret_cast<const lng2*>(hv[1]);
            i32x4 acc[4] = {};
#pragma unroll
            for (int kt = 0; kt < 4; kt++) {
                lng2 a = hp[kt * 4 + lq];
#pragma unroll
                for (int nt = 0; nt < 4; nt++)
                    acc[nt] = mfma_i8_k64(a, bfr[nt][kt], acc[nt]);
            }
            float gi = (float)acc[0][0] * swl[0] + bf_lo(xq1.x);
            float gf = (float)acc[1][0] * swl[1] + bf_hi(xq1.x);
            float gg = (float)acc[2][0] * swl[2] + bf_lo(xq1.y);
            float go = (float)acc[3][0] * swl[3] + bf_hi(xq1.y);
            float h = lstm_act(gi, gf, gg, go, cst);
            if (lq == 0) {
                h_out[((size_t)((u << 1) + 1) * SENT_BATCH + b) * HID + j] = h;
                hv[0][j] = (signed char)__float2int_rn(h * 127.f);
            }
            block_sync_lds();
        }
        xq0 = xq2; xq1 = xq3; xq2 = xn0; xq3 = xn1;
    }
}

// ---------------- K5: tag projection + log_softmax. 8 rows/block (W_tag staging amortized).
__global__ __launch_bounds__(256) void tag_logsoftmax(
        const float* __restrict__ h_out, const float* __restrict__ W_tag,
        const float* __restrict__ b_tag, float* __restrict__ out) {
    __shared__ float wt_s[TAGS * 257];      // 51.4 KB
    __shared__ float hr_s[8 * HID];         // 8 KB
    int tid = threadIdx.x;
    int row0 = blockIdx.x * 8;
#pragma unroll 2
    for (int i = 0; i < TAGS; i++) wt_s[i * 257 + tid] = W_tag[i * HID + tid];
#pragma unroll
    for (int w = 0; w < 8; w++) hr_s[w * HID + tid] = h_out[(size_t)(row0 + w) * HID + tid];
    __syncthreads();

    int w4 = tid >> 6, l = tid & 63;
#pragma unroll
    for (int rep = 0; rep < 2; rep++) {
        int w = rep * 4 + w4;
        float acc = 0.f;
        if (l < TAGS) {
            acc = b_tag[l];
            const float* hr = hr_s + w * HID;
            const float* wr = wt_s + l * 257;
#pragma unroll 4
            for (int k = 0; k < HID; k++) acc += hr[k] * wr[k];
        }
        float m = (l < TAGS) ? acc : -1e30f;
#pragma unroll
        for (int off = 32; off; off >>= 1) m = fmaxf(m, __shfl_xor(m, off, 64));
        float e = (l < TAGS) ? __builtin_amdgcn_exp2f((acc - m) * LOG2E) : 0.f;
        float ssum = e;
#pragma unroll
        for (int off = 32; off; off >>= 1) ssum += __shfl_xor(ssum, off, 64);
        float lse = m + __logf(ssum);
        if (l < TAGS) out[(size_t)(row0 + w) * TAGS + l] = acc - lse;
    }
}

extern "C" void kernel_launch(void* const* d_in, const int* in_sizes, int n_in,
                              void* d_out, int out_size, void* d_ws, size_t ws_size,
                              hipStream_t stream) {
    (void)in_sizes; (void)n_in; (void)out_size; (void)ws_size;
    const int*   sentences = (const int*)d_in[0];
    const int*   words     = (const int*)d_in[1];
    const float* word_emb  = (const float*)d_in[4];
    const float* char_emb  = (const float*)d_in[5];
    const float* Wih_c     = (const float*)d_in[6];
    const float* Whh_c     = (const float*)d_in[7];
    const float* bih_c     = (const float*)d_in[8];
    const float* bhh_c     = (const float*)d_in[9];
    const float* Wih_w     = (const float*)d_in[10];
    const float* Whh_w     = (const float*)d_in[11];
    const float* bih_w     = (const float*)d_in[12];
    const float* bhh_w     = (const float*)d_in[13];
    const float* W_tag     = (const float*)d_in[14];
    const float* b_tag     = (const float*)d_in[15];
    float* out = (float*)d_out;

    char* ws = (char*)d_ws;
    size_t off = 0;
    float* pre8 = (float*)(ws + off);                 off += 128 * 512 * sizeof(float);      // 256 KB
    signed char* wq = (signed char*)(ws + off);       off += 1024 * 256;                     // 256 KB
    float* sw = (float*)(ws + off);                   off += 1024 * sizeof(float);           // 4 KB
    unsigned short* wihb = (unsigned short*)(ws + off); off += (size_t)1024 * K_IN * 2;      // 512 KB
    off = (off + 255) & ~(size_t)255;
    float* cf = (float*)(ws + off);                   off += (size_t)SENT_LEN * SENT_BATCH * CHID * sizeof(float); // 8.4 MB
    uint2* xw8 = (uint2*)(ws + off);                  off += (size_t)SENT_LEN * SENT_BATCH * 256 * sizeof(uint2);  // 33.5 MB
    float* h_out = (float*)(ws + off);                off += (size_t)SENT_LEN * SENT_BATCH * HID * sizeof(float);  // 16.8 MB

    hipLaunchKernelGGL(prep_char, dim3(128), dim3(512), 0, stream,
                       Wih_c, char_emb, bih_c, bhh_c, pre8);
    hipLaunchKernelGGL(prep_wq, dim3(1024), dim3(64), 0, stream, Whh_w, Wih_w, wq, sw, wihb);
    hipLaunchKernelGGL(char_lstm, dim3(256), dim3(512), 0, stream,
                       words, Whh_c, pre8, cf);
    hipLaunchKernelGGL(xw_gemm, dim3(16, 256), dim3(256), 0, stream,
                       sentences, word_emb, cf, wihb, bih_w, bhh_w, xw8);
    hipLaunchKernelGGL(word_lstm, dim3(SENT_BATCH), dim3(1024), 0, stream,
                       xw8, wq, sw, h_out);
    hipLaunchKernelGGL(tag_logsoftmax, dim3((SENT_LEN * SENT_BATCH) / 8), dim3(256), 0, stream,
                       h_out, W_tag, b_tag, out);
}

// Round 8
// 945.333 us; speedup vs baseline: 1.1545x; 1.0104x over previous
//
#include <hip/hip_runtime.h>
#include <hip/hip_bf16.h>
#include <cstdint>

#define SENT_LEN   256
#define SENT_BATCH 64
#define WORD_LEN   16
#define EMB        128
#define HID        256
#define CEMB       64
#define CHID       128
#define TAGS       50
#define K_IN       (EMB + CHID)   // 256
#define LOG2E      1.44269504f
#define N2LOG2E    -2.88539008f   // -2*log2(e)

typedef __attribute__((ext_vector_type(8))) short short8;
typedef __attribute__((ext_vector_type(4))) float f32x4;
typedef __attribute__((ext_vector_type(4))) int   i32x4;
typedef __attribute__((ext_vector_type(2))) long  lng2;

__device__ __forceinline__ float rcpf(float x) { return __builtin_amdgcn_rcpf(x); }
// inputs pre-scaled by log2e: sig2(xl) = sigmoid(xl/log2e)
__device__ __forceinline__ float sig2(float xl) {
    return rcpf(1.f + __builtin_amdgcn_exp2f(-xl));
}
// tanh via sigmoid identity, clamp-free: tanh(x) = 2*sigmoid(2x)-1.
__device__ __forceinline__ float tanh2(float xl) {
    float e = __builtin_amdgcn_exp2f(-(xl + xl));
    return 2.f * rcpf(1.f + e) - 1.f;
}
__device__ __forceinline__ float lstm_act(float gi, float gf, float gg, float go, float& cst) {
    float c = sig2(gf) * cst + sig2(gi) * tanh2(gg);
    cst = c;
    float tc = 2.f * rcpf(1.f + __builtin_amdgcn_exp2f(N2LOG2E * c)) - 1.f;
    return sig2(go) * tc;
}
__device__ __forceinline__ float bf_lo(unsigned u) { return __uint_as_float(u << 16); }
__device__ __forceinline__ float bf_hi(unsigned u) { return __uint_as_float(u & 0xffff0000u); }
// branch-free RNE bf16 (finite inputs only)
__device__ __forceinline__ unsigned short f2bfu(float f) {
    unsigned u = __float_as_uint(f);
    u += 0x7fff + ((u >> 16) & 1);
    return (unsigned short)(u >> 16);
}
// CK-style barrier: drains LDS (lgkmcnt) only — global prefetches stay in flight.
__device__ __forceinline__ void block_sync_lds() {
    asm volatile("s_waitcnt lgkmcnt(0)\ns_barrier" ::: "memory");
}
// 16-byte K-fragment MFMA as two K=32 i8 calls (word_lstm path).
__device__ __forceinline__ i32x4 mfma_i8_k64(lng2 a, lng2 b, i32x4 c) {
    c = __builtin_amdgcn_mfma_i32_16x16x32_i8(a.x, b.x, c, 0, 0, 0);
    return __builtin_amdgcn_mfma_i32_16x16x32_i8(a.y, b.y, c, 0, 0, 0);
}
// quad_perm broadcast of quad-lane Q (pure-VALU cross-lane, no LDS pipe)
template<int Q> __device__ __forceinline__ float qbcast(float x) {
    return __int_as_float(__builtin_amdgcn_mov_dpp(
        __float_as_int(x), Q * 0x55, 0xF, 0xF, false));
}

// ---------------- K1a: pre8[ch*512 + (j*4+gt)] = s_e * LOG2E*(b_c[g] + Wih_c[g]·char_emb[ch])
// s_e = -2 for the g-gate (tanh), -1 otherwise: folds the exp2 argument scale in.
__global__ void prep_char(const float* __restrict__ Wih_c, const float* __restrict__ char_emb,
                          const float* __restrict__ bih_c, const float* __restrict__ bhh_c,
                          float* __restrict__ pre8) {
    int ch = blockIdx.x;      // 128
    int g  = threadIdx.x;     // 512
    float acc = bih_c[g] + bhh_c[g];
    const float* w = Wih_c + g * CEMB;
    const float* e = char_emb + ch * CEMB;
#pragma unroll
    for (int k = 0; k < CEMB; k++) acc += w[k] * e[k];
    int gt = g >> 7, j = g & 127;
    float s_e = (gt == 2) ? -2.f : -1.f;
    pre8[((ch * 128) + j) * 4 + gt] = acc * LOG2E * s_e;
}

// ---------------- K1b: per-row i8 quantization of Whh_w + bf16 copy of Wih_w row.
// 1024 blocks x 64.
__global__ void prep_wq(const float* __restrict__ Whh_w, const float* __restrict__ Wih_w,
                        signed char* __restrict__ wq, float* __restrict__ sw,
                        unsigned short* __restrict__ wihb) {
    int g = blockIdx.x;
    int lane = threadIdx.x;   // 64
    float4 v = reinterpret_cast<const float4*>(Whh_w + (size_t)g * HID)[lane];
    float m = fmaxf(fmaxf(fabsf(v.x), fabsf(v.y)), fmaxf(fabsf(v.z), fabsf(v.w)));
#pragma unroll
    for (int off = 32; off; off >>= 1) m = fmaxf(m, __shfl_xor(m, off, 64));
    m = fmaxf(m, 1e-20f);
    float inv = 127.f / m;
    int q0 = __float2int_rn(v.x * inv), q1 = __float2int_rn(v.y * inv);
    int q2 = __float2int_rn(v.z * inv), q3 = __float2int_rn(v.w * inv);
    int packed = (q0 & 255) | ((q1 & 255) << 8) | ((q2 & 255) << 16) | ((q3 & 255) << 24);
    reinterpret_cast<int*>(wq)[g * 64 + lane] = packed;
    if (lane == 0) sw[g] = m / 127.f;
    // bf16 copy of Wih_w row g (fused-GEMM B operand): bit-identical to f2bfu staging
    float4 wv = reinterpret_cast<const float4*>(Wih_w + (size_t)g * K_IN)[lane];
    uint2 p;
    p.x = (unsigned)f2bfu(wv.x) | ((unsigned)f2bfu(wv.y) << 16);
    p.y = (unsigned)f2bfu(wv.z) | ((unsigned)f2bfu(wv.w) << 16);
    reinterpret_cast<uint2*>(wihb + (size_t)g * K_IN)[lane] = p;
}

// ---------------- K2: char LSTM (proven R0 dot4 loop) + FUSED xw GEMM epilogue.
// 256 blocks x 1 chain, 512 threads (8 waves = 2/SIMD).
// Main loop: ONE GATE PER LANE, 32 sdot4/lane/step, h i8 in LDS (dbuf).
// The block keeps x = [bf16(emb[sid]) | bf16(h_final)] rows in LDS (xls[64][264],
// +8 pad breaks the 512B-stride bank conflict), then computes this t's entire
// xw8 slab (64 rows x 1024 gates, K=256) with bf16 MFMA after the final barrier —
// replaces the separate xw_gemm kernel and the cf global round-trip. All
// conversions/accumulation orders identical to the old xw_gemm.
__global__ __launch_bounds__(512, 1) void char_lstm(
        const int* __restrict__ words, const float* __restrict__ Whh_c,
        const float* __restrict__ pre8, const int* __restrict__ sentences,
        const float* __restrict__ word_emb, const unsigned short* __restrict__ wihb,
        const float* __restrict__ bih_w, const float* __restrict__ bhh_w,
        uint2* __restrict__ xw8) {
    int t    = blockIdx.x;               // chain
    int tid  = threadIdx.x;
    int lane = tid & 63, w = tid >> 6;   // 8 waves
    int nt   = lane & 3;
    int j    = w * 16 + (lane >> 2);
    int g    = nt * 128 + j;             // this lane's gate row

    __shared__ __align__(16) signed char hv[2][128];        // h as i8, dbuf
    __shared__ __align__(16) unsigned short xls[64][264];   // x rows bf16, pad 8

    // ---- per-lane i8 quant of this lane's Whh_c row
    const float4* wr = reinterpret_cast<const float4*>(Whh_c + (size_t)g * CHID);
    float mx = 1e-20f;
#pragma unroll
    for (int q = 0; q < 32; q++) {
        float4 f = wr[q];
        mx = fmaxf(mx, fmaxf(fmaxf(fabsf(f.x), fabsf(f.y)), fmaxf(fabsf(f.z), fabsf(f.w))));
    }
    float inv = 127.f / mx;
    int wqr[32];
#pragma unroll
    for (int q = 0; q < 32; q++) {
        float4 f = wr[q];
        wqr[q] = (__float2int_rn(f.x * inv) & 255)
               | ((__float2int_rn(f.y * inv) & 255) << 8)
               | ((__float2int_rn(f.z * inv) & 255) << 16)
               | ((__float2int_rn(f.w * inv) & 255) << 24);
    }
    float s_e   = (nt == 2) ? -2.f : -1.f;
    float swl_s = s_e * mx * (LOG2E / (127.f * 127.f));
    float m_a   = (nt == 2) ?  2.f :  1.f;
    float b_a   = (nt == 2) ? -1.f :  0.f;

    // ---- stage embedding half of x: xls[b][0:128] = bf16(word_emb[sid[b]])
    {
        int b  = tid >> 3;          // 0..63
        int c8 = tid & 7;           // 16 floats per thread
        int sid = sentences[t * 64 + b];
        const float4* ep = reinterpret_cast<const float4*>(
            word_emb + (size_t)sid * EMB + c8 * 16);
        float4 e0 = ep[0], e1 = ep[1], e2 = ep[2], e3 = ep[3];
        short8 v0, v1;
        v0[0] = (short)f2bfu(e0.x); v0[1] = (short)f2bfu(e0.y);
        v0[2] = (short)f2bfu(e0.z); v0[3] = (short)f2bfu(e0.w);
        v0[4] = (short)f2bfu(e1.x); v0[5] = (short)f2bfu(e1.y);
        v0[6] = (short)f2bfu(e1.z); v0[7] = (short)f2bfu(e1.w);
        v1[0] = (short)f2bfu(e2.x); v1[1] = (short)f2bfu(e2.y);
        v1[2] = (short)f2bfu(e2.z); v1[3] = (short)f2bfu(e2.w);
        v1[4] = (short)f2bfu(e3.x); v1[5] = (short)f2bfu(e3.y);
        v1[6] = (short)f2bfu(e3.z); v1[7] = (short)f2bfu(e3.w);
        *reinterpret_cast<short8*>(&xls[b][c8 * 16])     = v0;
        *reinterpret_cast<short8*>(&xls[b][c8 * 16 + 8]) = v1;
    }

    if (tid < 64) { reinterpret_cast<int*>(hv)[tid] = 0; }

    float cst = 0.f;
    int cid0 = words[t];
    int cid1 = words[SENT_LEN + t];
    float pl0 = pre8[(size_t)cid0 * 512 + tid];   // this lane's gate pre-input (folded)
    float pl1 = pre8[(size_t)cid1 * 512 + tid];
    int ci2 = words[2 * SENT_LEN + t];
    int ci3 = words[3 * SENT_LEN + t];
    __syncthreads();

    for (int u = 0; u < 512; u++) {          // steps 2u (A), 2u+1 (B)
        float pf0 = pre8[(size_t)ci2 * 512 + tid];
        float pf1 = pre8[(size_t)ci3 * 512 + tid];
        ci2 = words[(((u << 1) + 4) & 1023) * SENT_LEN + t];
        ci3 = words[(((u << 1) + 5) & 1023) * SENT_LEN + t];

        {   // step A: read hv[0] -> write hv[1]
            const i32x4* hp = reinterpret_cast<const i32x4*>(hv[0]);
            int a0 = 0, a1 = 0, a2 = 0, a3 = 0;
#pragma unroll
            for (int q = 0; q < 8; q++) {
                i32x4 hq = hp[q];
                a0 = __builtin_amdgcn_sdot4(hq.x, wqr[q * 4 + 0], a0, false);
                a1 = __builtin_amdgcn_sdot4(hq.y, wqr[q * 4 + 1], a1, false);
                a2 = __builtin_amdgcn_sdot4(hq.z, wqr[q * 4 + 2], a2, false);
                a3 = __builtin_amdgcn_sdot4(hq.w, wqr[q * 4 + 3], a3, false);
            }
            int s = (a0 + a1) + (a2 + a3);
            float e  = __builtin_amdgcn_exp2f(fmaf((float)s, swl_s, pl0));
            float av = m_a * rcpf(1.f + e) + b_a;     // own gate's nonlinearity
            float qi = qbcast<0>(av);                 // sig(i)
            float qf = qbcast<1>(av);                 // sig(f)
            float qg = qbcast<2>(av);                 // tanh(g)
            float qo = qbcast<3>(av);                 // sig(o)
            float c  = fmaf(qf, cst, qi * qg);
            cst = c;
            float tc = 2.f * rcpf(1.f + __builtin_amdgcn_exp2f(N2LOG2E * c)) - 1.f;
            float h  = qo * tc;
            if (nt == 0)
                hv[1][j] = (signed char)__float2int_rn(h * 127.f);
            block_sync_lds();
        }
        {   // step B: read hv[1] -> write hv[0]
            const i32x4* hp = reinterpret_cast<const i32x4*>(hv[1]);
            int a0 = 0, a1 = 0, a2 = 0, a3 = 0;
#pragma unroll
            for (int q = 0; q < 8; q++) {
                i32x4 hq = hp[q];
                a0 = __builtin_amdgcn_sdot4(hq.x, wqr[q * 4 + 0], a0, false);
                a1 = __builtin_amdgcn_sdot4(hq.y, wqr[q * 4 + 1], a1, false);
                a2 = __builtin_amdgcn_sdot4(hq.z, wqr[q * 4 + 2], a2, false);
                a3 = __builtin_amdgcn_sdot4(hq.w, wqr[q * 4 + 3], a3, false);
            }
            int s = (a0 + a1) + (a2 + a3);
            float e  = __builtin_amdgcn_exp2f(fmaf((float)s, swl_s, pl1));
            float av = m_a * rcpf(1.f + e) + b_a;
            float qi = qbcast<0>(av);
            float qf = qbcast<1>(av);
            float qg = qbcast<2>(av);
            float qo = qbcast<3>(av);
            float c  = fmaf(qf, cst, qi * qg);
            cst = c;
            float tc = 2.f * rcpf(1.f + __builtin_amdgcn_exp2f(N2LOG2E * c)) - 1.f;
            float h  = qo * tc;
            if (nt == 0) {
                hv[0][j] = (signed char)__float2int_rn(h * 127.f);
                if ((u & 7) == 7)
                    xls[u >> 3][128 + j] = f2bfu(h);   // x row's char half (bf16)
            }
            block_sync_lds();
        }
        pl0 = pf0; pl1 = pf1;
    }

    // ---- fused XW GEMM epilogue: xw8 slab for this t (64 rows x 1024 gates, K=256).
    // Wave w: m-tile mt = w&3 (rows mt*16..+15), j-tiles jt = (w>>2), +2, ... (8 of 16).
    // A frags from xls (loaded once, reused for all j-tiles); B frags 16B-contiguous
    // from wihb (L2). Mapping identical to the old xw_gemm.
    {
        int l15 = lane & 15, lq = lane >> 4;
        int mt  = w & 3;
        short8 af[8];
#pragma unroll
        for (int kt = 0; kt < 8; kt++)
            af[kt] = *reinterpret_cast<const short8*>(&xls[mt * 16 + l15][kt * 32 + lq * 8]);
#pragma unroll 1
        for (int jt = (w >> 2); jt < 16; jt += 2) {
            int j0 = jt * 16;
            f32x4 acc[4] = {{0.f,0.f,0.f,0.f},{0.f,0.f,0.f,0.f},
                            {0.f,0.f,0.f,0.f},{0.f,0.f,0.f,0.f}};
#pragma unroll
            for (int kt = 0; kt < 8; kt++) {
#pragma unroll
                for (int n2 = 0; n2 < 4; n2++) {
                    short8 bf = *reinterpret_cast<const short8*>(
                        wihb + (size_t)(n2 * 256 + j0 + l15) * K_IN + kt * 32 + lq * 8);
                    acc[n2] = __builtin_amdgcn_mfma_f32_16x16x32_bf16(
                        af[kt], bf, acc[n2], 0, 0, 0);
                }
            }
            float bb[4];
#pragma unroll
            for (int n2 = 0; n2 < 4; n2++)
                bb[n2] = bih_w[n2 * 256 + j0 + l15] + bhh_w[n2 * 256 + j0 + l15];
#pragma unroll
            for (int r = 0; r < 4; r++) {
                int br = mt * 16 + lq * 4 + r;       // chain index within this t
                uint2 o;
                o.x = (unsigned)f2bfu((acc[0][r] + bb[0]) * LOG2E)
                    | ((unsigned)f2bfu((acc[1][r] + bb[1]) * LOG2E) << 16);
                o.y = (unsigned)f2bfu((acc[2][r] + bb[2]) * LOG2E)
                    | ((unsigned)f2bfu((acc[3][r] + bb[3]) * LOG2E) << 16);
                xw8[((size_t)br * SENT_LEN + t) * 256 + j0 + l15] = o;
            }
        }
    }
}

// ---------------- K4: word LSTM. 64 blocks x 1 chain, 1024 threads (16 waves).
__global__ __launch_bounds__(1024, 1) void word_lstm(
        const uint2* __restrict__ xw8, const signed char* __restrict__ wq,
        const float* __restrict__ sw, float* __restrict__ h_out) {
    int b    = blockIdx.x;               // chain 0..63
    int tid  = threadIdx.x;
    int lane = tid & 63, w = tid >> 6;   // 16 waves
    int l15  = lane & 15, lq = lane >> 4;
    int j    = w * 16 + l15;

    __shared__ __align__(16) signed char hv[2][256];   // h as i8, dbuf, 512 B

    lng2 bfr[4][4];
    float swl[4];
#pragma unroll
    for (int nt = 0; nt < 4; nt++) {
        int g = nt * 256 + j;
        swl[nt] = sw[g] * (LOG2E / 127.f);
#pragma unroll
        for (int kt = 0; kt < 4; kt++)
            bfr[nt][kt] = reinterpret_cast<const lng2*>(wq + (size_t)g * HID + kt * 64 + lq * 16)[0];
    }
    if (tid < 128) { reinterpret_cast<int*>(hv)[tid] = 0; }

    const uint2* xwb = xw8 + (size_t)b * SENT_LEN * 256;   // this block's stream
    float cst = 0.f;
    uint2 xq0 = xwb[0 * 256 + j];
    uint2 xq1 = xwb[1 * 256 + j];
    uint2 xq2 = xwb[2 * 256 + j];
    uint2 xq3 = xwb[3 * 256 + j];
    __syncthreads();

    for (int u = 0; u < 128; u++) {          // steps 2u (A), 2u+1 (B)
        uint2 xn0 = xwb[((((u << 1) + 4) & 255)) * 256 + j];
        uint2 xn1 = xwb[((((u << 1) + 5) & 255)) * 256 + j];

        {   // step A: read hv[0] -> write hv[1]
            const lng2* hp = reinterpret_cast<const lng2*>(hv[0]);
            i32x4 acc[4] = {};
#pragma unroll
            for (int kt = 0; kt < 4; kt++) {
                lng2 a = hp[kt * 4 + lq];
#pragma unroll
                for (int nt = 0; nt < 4; nt++)
                    acc[nt] = mfma_i8_k64(a, bfr[nt][kt], acc[nt]);
            }
            float gi = (float)acc[0][0] * swl[0] + bf_lo(xq0.x);
            float gf = (float)acc[1][0] * swl[1] + bf_hi(xq0.x);
            float gg = (float)acc[2][0] * swl[2] + bf_lo(xq0.y);
            float go = (float)acc[3][0] * swl[3] + bf_hi(xq0.y);
            float h = lstm_act(gi, gf, gg, go, cst);
            if (lq == 0) {
                h_out[((size_t)(u << 1) * SENT_BATCH + b) * HID + j] = h;
                hv[1][j] = (signed char)__float2int_rn(h * 127.f);
            }
            block_sync_lds();
        }
        {   // step B: read hv[1] -> write hv[0]
            const lng2* hp = reinterpret_cast<const lng2*>(hv[1]);
            i32x4 acc[4] = {};
#pragma unroll
            for (int kt = 0; kt < 4; kt++) {
                lng2 a = hp[kt * 4 + lq];
#pragma unroll
                for (int nt = 0; nt < 4; nt++)
                    acc[nt] = mfma_i8_k64(a, bfr[nt][kt], acc[nt]);
            }
            float gi = (float)acc[0][0] * swl[0] + bf_lo(xq1.x);
            float gf = (float)acc[1][0] * swl[1] + bf_hi(xq1.x);
            float gg = (float)acc[2][0] * swl[2] + bf_lo(xq1.y);
            float go = (float)acc[3][0] * swl[3] + bf_hi(xq1.y);
            float h = lstm_act(gi, gf, gg, go, cst);
            if (lq == 0) {
                h_out[((size_t)((u << 1) + 1) * SENT_BATCH + b) * HID + j] = h;
                hv[0][j] = (signed char)__float2int_rn(h * 127.f);
            }
            block_sync_lds();
        }
        xq0 = xq2; xq1 = xq3; xq2 = xn0; xq3 = xn1;
    }
}

// ---------------- K5: tag projection + log_softmax. 8 rows/block (W_tag staging amortized).
__global__ __launch_bounds__(256) void tag_logsoftmax(
        const float* __restrict__ h_out, const float* __restrict__ W_tag,
        const float* __restrict__ b_tag, float* __restrict__ out) {
    __shared__ float wt_s[TAGS * 257];      // 51.4 KB
    __shared__ float hr_s[8 * HID];         // 8 KB
    int tid = threadIdx.x;
    int row0 = blockIdx.x * 8;
#pragma unroll 2
    for (int i = 0; i < TAGS; i++) wt_s[i * 257 + tid] = W_tag[i * HID + tid];
#pragma unroll
    for (int w = 0; w < 8; w++) hr_s[w * HID + tid] = h_out[(size_t)(row0 + w) * HID + tid];
    __syncthreads();

    int w4 = tid >> 6, l = tid & 63;
#pragma unroll
    for (int rep = 0; rep < 2; rep++) {
        int w = rep * 4 + w4;
        float acc = 0.f;
        if (l < TAGS) {
            acc = b_tag[l];
            const float* hr = hr_s + w * HID;
            const float* wr = wt_s + l * 257;
#pragma unroll 4
            for (int k = 0; k < HID; k++) acc += hr[k] * wr[k];
        }
        float m = (l < TAGS) ? acc : -1e30f;
#pragma unroll
        for (int off = 32; off; off >>= 1) m = fmaxf(m, __shfl_xor(m, off, 64));
        float e = (l < TAGS) ? __builtin_amdgcn_exp2f((acc - m) * LOG2E) : 0.f;
        float ssum = e;
#pragma unroll
        for (int off = 32; off; off >>= 1) ssum += __shfl_xor(ssum, off, 64);
        float lse = m + __logf(ssum);
        if (l < TAGS) out[(size_t)(row0 + w) * TAGS + l] = acc - lse;
    }
}

extern "C" void kernel_launch(void* const* d_in, const int* in_sizes, int n_in,
                              void* d_out, int out_size, void* d_ws, size_t ws_size,
                              hipStream_t stream) {
    (void)in_sizes; (void)n_in; (void)out_size; (void)ws_size;
    const int*   sentences = (const int*)d_in[0];
    const int*   words     = (const int*)d_in[1];
    const float* word_emb  = (const float*)d_in[4];
    const float* char_emb  = (const float*)d_in[5];
    const float* Wih_c     = (const float*)d_in[6];
    const float* Whh_c     = (const float*)d_in[7];
    const float* bih_c     = (const float*)d_in[8];
    const float* bhh_c     = (const float*)d_in[9];
    const float* Wih_w     = (const float*)d_in[10];
    const float* Whh_w     = (const float*)d_in[11];
    const float* bih_w     = (const float*)d_in[12];
    const float* bhh_w     = (const float*)d_in[13];
    const float* W_tag     = (const float*)d_in[14];
    const float* b_tag     = (const float*)d_in[15];
    float* out = (float*)d_out;

    char* ws = (char*)d_ws;
    size_t off = 0;
    float* pre8 = (float*)(ws + off);                 off += 128 * 512 * sizeof(float);      // 256 KB
    signed char* wq = (signed char*)(ws + off);       off += 1024 * 256;                     // 256 KB
    float* sw = (float*)(ws + off);                   off += 1024 * sizeof(float);           // 4 KB
    unsigned short* wihb = (unsigned short*)(ws + off); off += (size_t)1024 * K_IN * 2;      // 512 KB
    off = (off + 255) & ~(size_t)255;
    uint2* xw8 = (uint2*)(ws + off);                  off += (size_t)SENT_LEN * SENT_BATCH * 256 * sizeof(uint2);  // 33.5 MB
    float* h_out = (float*)(ws + off);                off += (size_t)SENT_LEN * SENT_BATCH * HID * sizeof(float);  // 16.8 MB

    hipLaunchKernelGGL(prep_char, dim3(128), dim3(512), 0, stream,
                       Wih_c, char_emb, bih_c, bhh_c, pre8);
    hipLaunchKernelGGL(prep_wq, dim3(1024), dim3(64), 0, stream, Whh_w, Wih_w, wq, sw, wihb);
    hipLaunchKernelGGL(char_lstm, dim3(256), dim3(512), 0, stream,
                       words, Whh_c, pre8, sentences, word_emb, wihb, bih_w, bhh_w, xw8);
    hipLaunchKernelGGL(word_lstm, dim3(SENT_BATCH), dim3(1024), 0, stream,
                       xw8, wq, sw, h_out);
    hipLaunchKernelGGL(tag_logsoftmax, dim3((SENT_LEN * SENT_BATCH) / 8), dim3(256), 0, stream,
                       h_out, W_tag, b_tag, out);
}

// Round 9
// 899.866 us; speedup vs baseline: 1.2128x; 1.0505x over previous
//
#include <hip/hip_runtime.h>
#include <hip/hip_bf16.h>
#include <cstdint>

#define SENT_LEN   256
#define SENT_BATCH 64
#define WORD_LEN   16
#define EMB        128
#define HID        256
#define CEMB       64
#define CHID       128
#define TAGS       50
#define K_IN       (EMB + CHID)   // 256
#define LOG2E      1.44269504f
#define N2LOG2E    -2.88539008f   // -2*log2(e)

typedef __attribute__((ext_vector_type(8))) short short8;
typedef __attribute__((ext_vector_type(4))) float f32x4;
typedef __attribute__((ext_vector_type(4))) int   i32x4;
typedef __attribute__((ext_vector_type(2))) long  lng2;

__device__ __forceinline__ float rcpf(float x) { return __builtin_amdgcn_rcpf(x); }
// inputs pre-scaled by log2e: sig2(xl) = sigmoid(xl/log2e)
__device__ __forceinline__ float sig2(float xl) {
    return rcpf(1.f + __builtin_amdgcn_exp2f(-xl));
}
// tanh via sigmoid identity, clamp-free: tanh(x) = 2*sigmoid(2x)-1.
__device__ __forceinline__ float tanh2(float xl) {
    float e = __builtin_amdgcn_exp2f(-(xl + xl));
    return 2.f * rcpf(1.f + e) - 1.f;
}
__device__ __forceinline__ float lstm_act(float gi, float gf, float gg, float go, float& cst) {
    float c = sig2(gf) * cst + sig2(gi) * tanh2(gg);
    cst = c;
    float tc = 2.f * rcpf(1.f + __builtin_amdgcn_exp2f(N2LOG2E * c)) - 1.f;
    return sig2(go) * tc;
}
__device__ __forceinline__ float bf_lo(unsigned u) { return __uint_as_float(u << 16); }
__device__ __forceinline__ float bf_hi(unsigned u) { return __uint_as_float(u & 0xffff0000u); }
// branch-free RNE bf16 (finite inputs only)
__device__ __forceinline__ unsigned short f2bfu(float f) {
    unsigned u = __float_as_uint(f);
    u += 0x7fff + ((u >> 16) & 1);
    return (unsigned short)(u >> 16);
}
// CK-style barrier: drains LDS (lgkmcnt) only — global prefetches stay in flight.
__device__ __forceinline__ void block_sync_lds() {
    asm volatile("s_waitcnt lgkmcnt(0)\ns_barrier" ::: "memory");
}
// 16-byte K-fragment MFMA as two K=32 i8 calls (word_lstm path).
__device__ __forceinline__ i32x4 mfma_i8_k64(lng2 a, lng2 b, i32x4 c) {
    c = __builtin_amdgcn_mfma_i32_16x16x32_i8(a.x, b.x, c, 0, 0, 0);
    return __builtin_amdgcn_mfma_i32_16x16x32_i8(a.y, b.y, c, 0, 0, 0);
}
// quad_perm broadcast of quad-lane Q (pure-VALU cross-lane, no LDS pipe)
template<int Q> __device__ __forceinline__ float qbcast(float x) {
    return __int_as_float(__builtin_amdgcn_mov_dpp(
        __float_as_int(x), Q * 0x55, 0xF, 0xF, false));
}

// ---------------- K1a: pre8[ch*512 + (j*4+gt)] = s_e * LOG2E*(b_c[g] + Wih_c[g]·char_emb[ch])
// s_e = -2 for the g-gate (tanh), -1 otherwise: folds the exp2 argument scale in.
__global__ void prep_char(const float* __restrict__ Wih_c, const float* __restrict__ char_emb,
                          const float* __restrict__ bih_c, const float* __restrict__ bhh_c,
                          float* __restrict__ pre8) {
    int ch = blockIdx.x;      // 128
    int g  = threadIdx.x;     // 512
    float acc = bih_c[g] + bhh_c[g];
    const float* w = Wih_c + g * CEMB;
    const float* e = char_emb + ch * CEMB;
#pragma unroll
    for (int k = 0; k < CEMB; k++) acc += w[k] * e[k];
    int gt = g >> 7, j = g & 127;
    float s_e = (gt == 2) ? -2.f : -1.f;
    pre8[((ch * 128) + j) * 4 + gt] = acc * LOG2E * s_e;
}

// ---------------- K1b: i8 quant of Whh_w + MFMA-FRAGMENT-ORDER bf16 copy of Wih_w.
// wihbF[((jt*4+n2)*8+kt)*64 + lane] = 16B frag: B-row n2*256+jt*16+(lane&15),
// k = kt*32+(lane>>4)*8 .. +7. Epilogue B loads become lane-contiguous (coalesced).
__global__ void prep_wq(const float* __restrict__ Whh_w, const float* __restrict__ Wih_w,
                        signed char* __restrict__ wq, float* __restrict__ sw,
                        unsigned short* __restrict__ wihb) {
    int g = blockIdx.x;
    int lane = threadIdx.x;   // 64
    float4 v = reinterpret_cast<const float4*>(Whh_w + (size_t)g * HID)[lane];
    float m = fmaxf(fmaxf(fabsf(v.x), fabsf(v.y)), fmaxf(fabsf(v.z), fabsf(v.w)));
#pragma unroll
    for (int off = 32; off; off >>= 1) m = fmaxf(m, __shfl_xor(m, off, 64));
    m = fmaxf(m, 1e-20f);
    float inv = 127.f / m;
    int q0 = __float2int_rn(v.x * inv), q1 = __float2int_rn(v.y * inv);
    int q2 = __float2int_rn(v.z * inv), q3 = __float2int_rn(v.w * inv);
    int packed = (q0 & 255) | ((q1 & 255) << 8) | ((q2 & 255) << 16) | ((q3 & 255) << 24);
    reinterpret_cast<int*>(wq)[g * 64 + lane] = packed;
    if (lane == 0) sw[g] = m / 127.f;
    // fragment-order bf16 copy of Wih_w row g (bit-identical values to f2bfu staging)
    float4 wv = reinterpret_cast<const float4*>(Wih_w + (size_t)g * K_IN)[lane];
    uint2 p;
    p.x = (unsigned)f2bfu(wv.x) | ((unsigned)f2bfu(wv.y) << 16);
    p.y = (unsigned)f2bfu(wv.z) | ((unsigned)f2bfu(wv.w) << 16);
    int n2 = g >> 8, j = g & 255, jt = j >> 4, l15 = j & 15;
    int k0 = lane * 4;
    int kt = k0 >> 5, lqf = (k0 >> 3) & 3;
    size_t fidx = ((size_t)(jt * 4 + n2) * 8 + kt) * 64 + (lqf * 16 + l15);
    char* dst = (char*)wihb + fidx * 16 + (size_t)(k0 & 4) * 2;
    *reinterpret_cast<uint2*>(dst) = p;
}

// ---------------- K2: char LSTM (proven R0 dot4 loop) + FUSED xw GEMM epilogue.
// 256 blocks x 1 chain, 512 threads (8 waves = 2/SIMD).
// Main loop: ONE GATE PER LANE, 32 sdot4/lane/step, h i8 in LDS (dbuf).
// x rows ([bf16 emb | bf16 h_final]) kept in xls[64][264] (+8 pad); after the final
// barrier the block computes this t's whole xw8 slab (64x1024, K=256) with bf16 MFMA.
// B frags stream COALESCED from the fragment-order wihbF.
__global__ __launch_bounds__(512, 1) void char_lstm(
        const int* __restrict__ words, const float* __restrict__ Whh_c,
        const float* __restrict__ pre8, const int* __restrict__ sentences,
        const float* __restrict__ word_emb, const unsigned short* __restrict__ wihb,
        const float* __restrict__ bih_w, const float* __restrict__ bhh_w,
        uint2* __restrict__ xw8) {
    int t    = blockIdx.x;               // chain
    int tid  = threadIdx.x;
    int lane = tid & 63, w = tid >> 6;   // 8 waves
    int nt   = lane & 3;
    int j    = w * 16 + (lane >> 2);
    int g    = nt * 128 + j;             // this lane's gate row

    __shared__ __align__(16) signed char hv[2][128];        // h as i8, dbuf
    __shared__ __align__(16) unsigned short xls[64][264];   // x rows bf16, pad 8

    // ---- per-lane i8 quant of this lane's Whh_c row
    const float4* wr = reinterpret_cast<const float4*>(Whh_c + (size_t)g * CHID);
    float mx = 1e-20f;
#pragma unroll
    for (int q = 0; q < 32; q++) {
        float4 f = wr[q];
        mx = fmaxf(mx, fmaxf(fmaxf(fabsf(f.x), fabsf(f.y)), fmaxf(fabsf(f.z), fabsf(f.w))));
    }
    float inv = 127.f / mx;
    int wqr[32];
#pragma unroll
    for (int q = 0; q < 32; q++) {
        float4 f = wr[q];
        wqr[q] = (__float2int_rn(f.x * inv) & 255)
               | ((__float2int_rn(f.y * inv) & 255) << 8)
               | ((__float2int_rn(f.z * inv) & 255) << 16)
               | ((__float2int_rn(f.w * inv) & 255) << 24);
    }
    float s_e   = (nt == 2) ? -2.f : -1.f;
    float swl_s = s_e * mx * (LOG2E / (127.f * 127.f));
    float m_a   = (nt == 2) ?  2.f :  1.f;
    float b_a   = (nt == 2) ? -1.f :  0.f;

    // ---- stage embedding half of x: xls[b][0:128] = bf16(word_emb[sid[b]])
    {
        int b  = tid >> 3;          // 0..63
        int c8 = tid & 7;           // 16 floats per thread
        int sid = sentences[t * 64 + b];
        const float4* ep = reinterpret_cast<const float4*>(
            word_emb + (size_t)sid * EMB + c8 * 16);
        float4 e0 = ep[0], e1 = ep[1], e2 = ep[2], e3 = ep[3];
        short8 v0, v1;
        v0[0] = (short)f2bfu(e0.x); v0[1] = (short)f2bfu(e0.y);
        v0[2] = (short)f2bfu(e0.z); v0[3] = (short)f2bfu(e0.w);
        v0[4] = (short)f2bfu(e1.x); v0[5] = (short)f2bfu(e1.y);
        v0[6] = (short)f2bfu(e1.z); v0[7] = (short)f2bfu(e1.w);
        v1[0] = (short)f2bfu(e2.x); v1[1] = (short)f2bfu(e2.y);
        v1[2] = (short)f2bfu(e2.z); v1[3] = (short)f2bfu(e2.w);
        v1[4] = (short)f2bfu(e3.x); v1[5] = (short)f2bfu(e3.y);
        v1[6] = (short)f2bfu(e3.z); v1[7] = (short)f2bfu(e3.w);
        *reinterpret_cast<short8*>(&xls[b][c8 * 16])     = v0;
        *reinterpret_cast<short8*>(&xls[b][c8 * 16 + 8]) = v1;
    }

    if (tid < 64) { reinterpret_cast<int*>(hv)[tid] = 0; }

    float cst = 0.f;
    int cid0 = words[t];
    int cid1 = words[SENT_LEN + t];
    float pl0 = pre8[(size_t)cid0 * 512 + tid];   // this lane's gate pre-input (folded)
    float pl1 = pre8[(size_t)cid1 * 512 + tid];
    int ci2 = words[2 * SENT_LEN + t];
    int ci3 = words[3 * SENT_LEN + t];
    __syncthreads();

    for (int u = 0; u < 512; u++) {          // steps 2u (A), 2u+1 (B)
        float pf0 = pre8[(size_t)ci2 * 512 + tid];
        float pf1 = pre8[(size_t)ci3 * 512 + tid];
        ci2 = words[(((u << 1) + 4) & 1023) * SENT_LEN + t];
        ci3 = words[(((u << 1) + 5) & 1023) * SENT_LEN + t];

        {   // step A: read hv[0] -> write hv[1]
            const i32x4* hp = reinterpret_cast<const i32x4*>(hv[0]);
            int a0 = 0, a1 = 0, a2 = 0, a3 = 0;
#pragma unroll
            for (int q = 0; q < 8; q++) {
                i32x4 hq = hp[q];
                a0 = __builtin_amdgcn_sdot4(hq.x, wqr[q * 4 + 0], a0, false);
                a1 = __builtin_amdgcn_sdot4(hq.y, wqr[q * 4 + 1], a1, false);
                a2 = __builtin_amdgcn_sdot4(hq.z, wqr[q * 4 + 2], a2, false);
                a3 = __builtin_amdgcn_sdot4(hq.w, wqr[q * 4 + 3], a3, false);
            }
            int s = (a0 + a1) + (a2 + a3);
            float e  = __builtin_amdgcn_exp2f(fmaf((float)s, swl_s, pl0));
            float av = m_a * rcpf(1.f + e) + b_a;     // own gate's nonlinearity
            float qi = qbcast<0>(av);                 // sig(i)
            float qf = qbcast<1>(av);                 // sig(f)
            float qg = qbcast<2>(av);                 // tanh(g)
            float qo = qbcast<3>(av);                 // sig(o)
            float c  = fmaf(qf, cst, qi * qg);
            cst = c;
            float tc = 2.f * rcpf(1.f + __builtin_amdgcn_exp2f(N2LOG2E * c)) - 1.f;
            float h  = qo * tc;
            if (nt == 0)
                hv[1][j] = (signed char)__float2int_rn(h * 127.f);
            block_sync_lds();
        }
        {   // step B: read hv[1] -> write hv[0]
            const i32x4* hp = reinterpret_cast<const i32x4*>(hv[1]);
            int a0 = 0, a1 = 0, a2 = 0, a3 = 0;
#pragma unroll
            for (int q = 0; q < 8; q++) {
                i32x4 hq = hp[q];
                a0 = __builtin_amdgcn_sdot4(hq.x, wqr[q * 4 + 0], a0, false);
                a1 = __builtin_amdgcn_sdot4(hq.y, wqr[q * 4 + 1], a1, false);
                a2 = __builtin_amdgcn_sdot4(hq.z, wqr[q * 4 + 2], a2, false);
                a3 = __builtin_amdgcn_sdot4(hq.w, wqr[q * 4 + 3], a3, false);
            }
            int s = (a0 + a1) + (a2 + a3);
            float e  = __builtin_amdgcn_exp2f(fmaf((float)s, swl_s, pl1));
            float av = m_a * rcpf(1.f + e) + b_a;
            float qi = qbcast<0>(av);
            float qf = qbcast<1>(av);
            float qg = qbcast<2>(av);
            float qo = qbcast<3>(av);
            float c  = fmaf(qf, cst, qi * qg);
            cst = c;
            float tc = 2.f * rcpf(1.f + __builtin_amdgcn_exp2f(N2LOG2E * c)) - 1.f;
            float h  = qo * tc;
            if (nt == 0) {
                hv[0][j] = (signed char)__float2int_rn(h * 127.f);
                if ((u & 7) == 7)
                    xls[u >> 3][128 + j] = f2bfu(h);   // x row's char half (bf16)
            }
            block_sync_lds();
        }
        pl0 = pf0; pl1 = pf1;
    }

    // ---- fused XW GEMM epilogue (64 rows x 1024 gates, K=256).
    // Wave w: m-tile mt = w&3, j-tiles jt = (w>>2), +2, ... (8 of 16).
    // A frags from xls (reused across j-tiles); B frags COALESCED from wihbF:
    // frag base ((jt*4+n2)*8+kt)*64, + lane -> contiguous 1KB per instruction.
    {
        int l15 = lane & 15, lq = lane >> 4;
        int mt  = w & 3;
        short8 af[8];
#pragma unroll
        for (int kt = 0; kt < 8; kt++)
            af[kt] = *reinterpret_cast<const short8*>(&xls[mt * 16 + l15][kt * 32 + lq * 8]);
        const short8* bF = reinterpret_cast<const short8*>(wihb);
#pragma unroll 1
        for (int jt = (w >> 2); jt < 16; jt += 2) {
            int j0 = jt * 16;
            const short8* bJ = bF + (size_t)jt * 4 * 8 * 64 + lane;
            f32x4 acc[4] = {{0.f,0.f,0.f,0.f},{0.f,0.f,0.f,0.f},
                            {0.f,0.f,0.f,0.f},{0.f,0.f,0.f,0.f}};
#pragma unroll
            for (int kt = 0; kt < 8; kt++) {
#pragma unroll
                for (int n2 = 0; n2 < 4; n2++) {
                    short8 bf = bJ[(n2 * 8 + kt) * 64];
                    acc[n2] = __builtin_amdgcn_mfma_f32_16x16x32_bf16(
                        af[kt], bf, acc[n2], 0, 0, 0);
                }
            }
            float bb[4];
#pragma unroll
            for (int n2 = 0; n2 < 4; n2++)
                bb[n2] = bih_w[n2 * 256 + j0 + l15] + bhh_w[n2 * 256 + j0 + l15];
#pragma unroll
            for (int r = 0; r < 4; r++) {
                int br = mt * 16 + lq * 4 + r;       // chain index within this t
                uint2 o;
                o.x = (unsigned)f2bfu((acc[0][r] + bb[0]) * LOG2E)
                    | ((unsigned)f2bfu((acc[1][r] + bb[1]) * LOG2E) << 16);
                o.y = (unsigned)f2bfu((acc[2][r] + bb[2]) * LOG2E)
                    | ((unsigned)f2bfu((acc[3][r] + bb[3]) * LOG2E) << 16);
                xw8[((size_t)br * SENT_LEN + t) * 256 + j0 + l15] = o;
            }
        }
    }
}

// ---------------- K4: word LSTM. 64 blocks x 1 chain, 1024 threads (16 waves).
__global__ __launch_bounds__(1024, 1) void word_lstm(
        const uint2* __restrict__ xw8, const signed char* __restrict__ wq,
        const float* __restrict__ sw, float* __restrict__ h_out) {
    int b    = blockIdx.x;               // chain 0..63
    int tid  = threadIdx.x;
    int lane = tid & 63, w = tid >> 6;   // 16 waves
    int l15  = lane & 15, lq = lane >> 4;
    int j    = w * 16 + l15;

    __shared__ __align__(16) signed char hv[2][256];   // h as i8, dbuf, 512 B

    lng2 bfr[4][4];
    float swl[4];
#pragma unroll
    for (int nt = 0; nt < 4; nt++) {
        int g = nt * 256 + j;
        swl[nt] = sw[g] * (LOG2E / 127.f);
#pragma unroll
        for (int kt = 0; kt < 4; kt++)
            bfr[nt][kt] = reinterpret_cast<const lng2*>(wq + (size_t)g * HID + kt * 64 + lq * 16)[0];
    }
    if (tid < 128) { reinterpret_cast<int*>(hv)[tid] = 0; }

    const uint2* xwb = xw8 + (size_t)b * SENT_LEN * 256;   // this block's stream
    float cst = 0.f;
    uint2 xq0 = xwb[0 * 256 + j];
    uint2 xq1 = xwb[1 * 256 + j];
    uint2 xq2 = xwb[2 * 256 + j];
    uint2 xq3 = xwb[3 * 256 + j];
    __syncthreads();

    for (int u = 0; u < 128; u++) {          // steps 2u (A), 2u+1 (B)
        uint2 xn0 = xwb[((((u << 1) + 4) & 255)) * 256 + j];
        uint2 xn1 = xwb[((((u << 1) + 5) & 255)) * 256 + j];

        {   // step A: read hv[0] -> write hv[1]
            const lng2* hp = reinterpret_cast<const lng2*>(hv[0]);
            i32x4 acc[4] = {};
#pragma unroll
            for (int kt = 0; kt < 4; kt++) {
                lng2 a = hp[kt * 4 + lq];
#pragma unroll
                for (int nt = 0; nt < 4; nt++)
                    acc[nt] = mfma_i8_k64(a, bfr[nt][kt], acc[nt]);
            }
            float gi = (float)acc[0][0] * swl[0] + bf_lo(xq0.x);
            float gf = (float)acc[1][0] * swl[1] + bf_hi(xq0.x);
            float gg = (float)acc[2][0] * swl[2] + bf_lo(xq0.y);
            float go = (float)acc[3][0] * swl[3] + bf_hi(xq0.y);
            float h = lstm_act(gi, gf, gg, go, cst);
            if (lq == 0) {
                h_out[((size_t)(u << 1) * SENT_BATCH + b) * HID + j] = h;
                hv[1][j] = (signed char)__float2int_rn(h * 127.f);
            }
            block_sync_lds();
        }
        {   // step B: read hv[1] -> write hv[0]
            const lng2* hp = reinterpret_cast<const lng2*>(hv[1]);
            i32x4 acc[4] = {};
#pragma unroll
            for (int kt = 0; kt < 4; kt++) {
                lng2 a = hp[kt * 4 + lq];
#pragma unroll
                for (int nt = 0; nt < 4; nt++)
                    acc[nt] = mfma_i8_k64(a, bfr[nt][kt], acc[nt]);
            }
            float gi = (float)acc[0][0] * swl[0] + bf_lo(xq1.x);
            float gf = (float)acc[1][0] * swl[1] + bf_hi(xq1.x);
            float gg = (float)acc[2][0] * swl[2] + bf_lo(xq1.y);
            float go = (float)acc[3][0] * swl[3] + bf_hi(xq1.y);
            float h = lstm_act(gi, gf, gg, go, cst);
            if (lq == 0) {
                h_out[((size_t)((u << 1) + 1) * SENT_BATCH + b) * HID + j] = h;
                hv[0][j] = (signed char)__float2int_rn(h * 127.f);
            }
            block_sync_lds();
        }
        xq0 = xq2; xq1 = xq3; xq2 = xn0; xq3 = xn1;
    }
}

// ---------------- K5: tag projection + log_softmax. 8 rows/block (W_tag staging amortized).
__global__ __launch_bounds__(256) void tag_logsoftmax(
        const float* __restrict__ h_out, const float* __restrict__ W_tag,
        const float* __restrict__ b_tag, float* __restrict__ out) {
    __shared__ float wt_s[TAGS * 257];      // 51.4 KB
    __shared__ float hr_s[8 * HID];         // 8 KB
    int tid = threadIdx.x;
    int row0 = blockIdx.x * 8;
#pragma unroll 2
    for (int i = 0; i < TAGS; i++) wt_s[i * 257 + tid] = W_tag[i * HID + tid];
#pragma unroll
    for (int w = 0; w < 8; w++) hr_s[w * HID + tid] = h_out[(size_t)(row0 + w) * HID + tid];
    __syncthreads();

    int w4 = tid >> 6, l = tid & 63;
#pragma unroll
    for (int rep = 0; rep < 2; rep++) {
        int w = rep * 4 + w4;
        float acc = 0.f;
        if (l < TAGS) {
            acc = b_tag[l];
            const float* hr = hr_s + w * HID;
            const float* wr = wt_s + l * 257;
#pragma unroll 4
            for (int k = 0; k < HID; k++) acc += hr[k] * wr[k];
        }
        float m = (l < TAGS) ? acc : -1e30f;
#pragma unroll
        for (int off = 32; off; off >>= 1) m = fmaxf(m, __shfl_xor(m, off, 64));
        float e = (l < TAGS) ? __builtin_amdgcn_exp2f((acc - m) * LOG2E) : 0.f;
        float ssum = e;
#pragma unroll
        for (int off = 32; off; off >>= 1) ssum += __shfl_xor(ssum, off, 64);
        float lse = m + __logf(ssum);
        if (l < TAGS) out[(size_t)(row0 + w) * TAGS + l] = acc - lse;
    }
}

extern "C" void kernel_launch(void* const* d_in, const int* in_sizes, int n_in,
                              void* d_out, int out_size, void* d_ws, size_t ws_size,
                              hipStream_t stream) {
    (void)in_sizes; (void)n_in; (void)out_size; (void)ws_size;
    const int*   sentences = (const int*)d_in[0];
    const int*   words     = (const int*)d_in[1];
    const float* word_emb  = (const float*)d_in[4];
    const float* char_emb  = (const float*)d_in[5];
    const float* Wih_c     = (const float*)d_in[6];
    const float* Whh_c     = (const float*)d_in[7];
    const float* bih_c     = (const float*)d_in[8];
    const float* bhh_c     = (const float*)d_in[9];
    const float* Wih_w     = (const float*)d_in[10];
    const float* Whh_w     = (const float*)d_in[11];
    const float* bih_w     = (const float*)d_in[12];
    const float* bhh_w     = (const float*)d_in[13];
    const float* W_tag     = (const float*)d_in[14];
    const float* b_tag     = (const float*)d_in[15];
    float* out = (float*)d_out;

    char* ws = (char*)d_ws;
    size_t off = 0;
    float* pre8 = (float*)(ws + off);                 off += 128 * 512 * sizeof(float);      // 256 KB
    signed char* wq = (signed char*)(ws + off);       off += 1024 * 256;                     // 256 KB
    float* sw = (float*)(ws + off);                   off += 1024 * sizeof(float);           // 4 KB
    unsigned short* wihb = (unsigned short*)(ws + off); off += (size_t)1024 * K_IN * 2;      // 512 KB (fragment order)
    off = (off + 255) & ~(size_t)255;
    uint2* xw8 = (uint2*)(ws + off);                  off += (size_t)SENT_LEN * SENT_BATCH * 256 * sizeof(uint2);  // 33.5 MB
    float* h_out = (float*)(ws + off);                off += (size_t)SENT_LEN * SENT_BATCH * HID * sizeof(float);  // 16.8 MB

    hipLaunchKernelGGL(prep_char, dim3(128), dim3(512), 0, stream,
                       Wih_c, char_emb, bih_c, bhh_c, pre8);
    hipLaunchKernelGGL(prep_wq, dim3(1024), dim3(64), 0, stream, Whh_w, Wih_w, wq, sw, wihb);
    hipLaunchKernelGGL(char_lstm, dim3(256), dim3(512), 0, stream,
                       words, Whh_c, pre8, sentences, word_emb, wihb, bih_w, bhh_w, xw8);
    hipLaunchKernelGGL(word_lstm, dim3(SENT_BATCH), dim3(1024), 0, stream,
                       xw8, wq, sw, h_out);
    hipLaunchKernelGGL(tag_logsoftmax, dim3((SENT_LEN * SENT_BATCH) / 8), dim3(256), 0, stream,
                       h_out, W_tag, b_tag, out);
}

// Round 10
// 810.820 us; speedup vs baseline: 1.3460x; 1.1098x over previous
//
#include <hip/hip_runtime.h>
#include <hip/hip_bf16.h>
#include <cstdint>

#define SENT_LEN   256
#define SENT_BATCH 64
#define WORD_LEN   16
#define EMB        128
#define HID        256
#define CEMB       64
#define CHID       128
#define TAGS       50
#define K_IN       (EMB + CHID)   // 256
#define LOG2E      1.44269504f
#define N2LOG2E    -2.88539008f   // -2*log2(e)

typedef __attribute__((ext_vector_type(8))) short short8;
typedef __attribute__((ext_vector_type(4))) float f32x4;
typedef __attribute__((ext_vector_type(4))) int   i32x4;
typedef __attribute__((ext_vector_type(2))) long  lng2;

__device__ __forceinline__ float rcpf(float x) { return __builtin_amdgcn_rcpf(x); }
// inputs pre-scaled by log2e: sig2(xl) = sigmoid(xl/log2e)
__device__ __forceinline__ float sig2(float xl) {
    return rcpf(1.f + __builtin_amdgcn_exp2f(-xl));
}
// tanh via sigmoid identity, clamp-free: tanh(x) = 2*sigmoid(2x)-1.
__device__ __forceinline__ float tanh2(float xl) {
    float e = __builtin_amdgcn_exp2f(-(xl + xl));
    return 2.f * rcpf(1.f + e) - 1.f;
}
__device__ __forceinline__ float lstm_act(float gi, float gf, float gg, float go, float& cst) {
    float c = sig2(gf) * cst + sig2(gi) * tanh2(gg);
    cst = c;
    float tc = 2.f * rcpf(1.f + __builtin_amdgcn_exp2f(N2LOG2E * c)) - 1.f;
    return sig2(go) * tc;
}
__device__ __forceinline__ float bf_lo(unsigned u) { return __uint_as_float(u << 16); }
__device__ __forceinline__ float bf_hi(unsigned u) { return __uint_as_float(u & 0xffff0000u); }
// branch-free RNE bf16 (finite inputs only)
__device__ __forceinline__ unsigned short f2bfu(float f) {
    unsigned u = __float_as_uint(f);
    u += 0x7fff + ((u >> 16) & 1);
    return (unsigned short)(u >> 16);
}
// CK-style barrier: drains LDS (lgkmcnt) only — global prefetches stay in flight.
__device__ __forceinline__ void block_sync_lds() {
    asm volatile("s_waitcnt lgkmcnt(0)\ns_barrier" ::: "memory");
}
// 16-byte K-fragment i8 MFMA: native gfx950 K=64 instruction (single issue).
// Shared A/B k-permutation (lane chunk (l>>4)*16+p <-> source k = base+lq*16+p)
// preserves the dot; integer accumulate -> bit-identical to the chained K=32 pair.
__device__ __forceinline__ i32x4 mfma_i8_k64(lng2 a, lng2 b, i32x4 c) {
    i32x4 av = __builtin_bit_cast(i32x4, a);
    i32x4 bv = __builtin_bit_cast(i32x4, b);
    return __builtin_amdgcn_mfma_i32_16x16x64_i8(av, bv, c, 0, 0, 0);
}
// quad_perm broadcast of quad-lane Q (pure-VALU cross-lane, no LDS pipe)
template<int Q> __device__ __forceinline__ float qbcast(float x) {
    return __int_as_float(__builtin_amdgcn_mov_dpp(
        __float_as_int(x), Q * 0x55, 0xF, 0xF, false));
}

// ---------------- K1a: pre8[ch*512 + (j*4+gt)] = s_e * LOG2E*(b_c[g] + Wih_c[g]·char_emb[ch])
// s_e = -2 for the g-gate (tanh), -1 otherwise. float4 loads; fma order as scalar loop.
__global__ void prep_char(const float* __restrict__ Wih_c, const float* __restrict__ char_emb,
                          const float* __restrict__ bih_c, const float* __restrict__ bhh_c,
                          float* __restrict__ pre8) {
    int ch = blockIdx.x;      // 128
    int g  = threadIdx.x;     // 512
    float acc = bih_c[g] + bhh_c[g];
    const float4* w4 = reinterpret_cast<const float4*>(Wih_c + (size_t)g * CEMB);
    const float4* e4 = reinterpret_cast<const float4*>(char_emb + (size_t)ch * CEMB);
#pragma unroll
    for (int k = 0; k < CEMB / 4; k++) {
        float4 wv = w4[k], ev = e4[k];
        acc += wv.x * ev.x; acc += wv.y * ev.y;
        acc += wv.z * ev.z; acc += wv.w * ev.w;
    }
    int gt = g >> 7, j = g & 127;
    float s_e = (gt == 2) ? -2.f : -1.f;
    pre8[((ch * 128) + j) * 4 + gt] = acc * LOG2E * s_e;
}

// ---------------- K1b: i8 quant of Whh_w + MFMA-FRAGMENT-ORDER bf16 copy of Wih_w.
// wihbF[((jt*4+n2)*8+kt)*64 + lane] = 16B frag: B-row n2*256+jt*16+(lane&15),
// k = kt*32+(lane>>4)*8 .. +7. Epilogue B loads become lane-contiguous (coalesced).
__global__ void prep_wq(const float* __restrict__ Whh_w, const float* __restrict__ Wih_w,
                        signed char* __restrict__ wq, float* __restrict__ sw,
                        unsigned short* __restrict__ wihb) {
    int g = blockIdx.x;
    int lane = threadIdx.x;   // 64
    float4 v = reinterpret_cast<const float4*>(Whh_w + (size_t)g * HID)[lane];
    float m = fmaxf(fmaxf(fabsf(v.x), fabsf(v.y)), fmaxf(fabsf(v.z), fabsf(v.w)));
#pragma unroll
    for (int off = 32; off; off >>= 1) m = fmaxf(m, __shfl_xor(m, off, 64));
    m = fmaxf(m, 1e-20f);
    float inv = 127.f / m;
    int q0 = __float2int_rn(v.x * inv), q1 = __float2int_rn(v.y * inv);
    int q2 = __float2int_rn(v.z * inv), q3 = __float2int_rn(v.w * inv);
    int packed = (q0 & 255) | ((q1 & 255) << 8) | ((q2 & 255) << 16) | ((q3 & 255) << 24);
    reinterpret_cast<int*>(wq)[g * 64 + lane] = packed;
    if (lane == 0) sw[g] = m / 127.f;
    // fragment-order bf16 copy of Wih_w row g (bit-identical values to f2bfu staging)
    float4 wv = reinterpret_cast<const float4*>(Wih_w + (size_t)g * K_IN)[lane];
    uint2 p;
    p.x = (unsigned)f2bfu(wv.x) | ((unsigned)f2bfu(wv.y) << 16);
    p.y = (unsigned)f2bfu(wv.z) | ((unsigned)f2bfu(wv.w) << 16);
    int n2 = g >> 8, j = g & 255, jt = j >> 4, l15 = j & 15;
    int k0 = lane * 4;
    int kt = k0 >> 5, lqf = (k0 >> 3) & 3;
    size_t fidx = ((size_t)(jt * 4 + n2) * 8 + kt) * 64 + (lqf * 16 + l15);
    char* dst = (char*)wihb + fidx * 16 + (size_t)(k0 & 4) * 2;
    *reinterpret_cast<uint2*>(dst) = p;
}

// ---------------- K2: char LSTM (proven R0 dot4 loop) + FUSED xw GEMM epilogue.
// 256 blocks x 1 chain, 512 threads (8 waves = 2/SIMD).
// Main loop: ONE GATE PER LANE, 32 sdot4/lane/step, h i8 in LDS (dbuf).
// x rows ([bf16 emb | bf16 h_final]) kept in xls[64][264] (+8 pad); after the final
// barrier the block computes this t's whole xw8 slab (64x1024, K=256) with bf16 MFMA.
// B frags stream COALESCED from the fragment-order wihbF.
__global__ __launch_bounds__(512, 1) void char_lstm(
        const int* __restrict__ words, const float* __restrict__ Whh_c,
        const float* __restrict__ pre8, const int* __restrict__ sentences,
        const float* __restrict__ word_emb, const unsigned short* __restrict__ wihb,
        const float* __restrict__ bih_w, const float* __restrict__ bhh_w,
        uint2* __restrict__ xw8) {
    int t    = blockIdx.x;               // chain
    int tid  = threadIdx.x;
    int lane = tid & 63, w = tid >> 6;   // 8 waves
    int nt   = lane & 3;
    int j    = w * 16 + (lane >> 2);
    int g    = nt * 128 + j;             // this lane's gate row

    __shared__ __align__(16) signed char hv[2][128];        // h as i8, dbuf
    __shared__ __align__(16) unsigned short xls[64][264];   // x rows bf16, pad 8

    // ---- per-lane i8 quant of this lane's Whh_c row
    const float4* wr = reinterpret_cast<const float4*>(Whh_c + (size_t)g * CHID);
    float mx = 1e-20f;
#pragma unroll
    for (int q = 0; q < 32; q++) {
        float4 f = wr[q];
        mx = fmaxf(mx, fmaxf(fmaxf(fabsf(f.x), fabsf(f.y)), fmaxf(fabsf(f.z), fabsf(f.w))));
    }
    float inv = 127.f / mx;
    int wqr[32];
#pragma unroll
    for (int q = 0; q < 32; q++) {
        float4 f = wr[q];
        wqr[q] = (__float2int_rn(f.x * inv) & 255)
               | ((__float2int_rn(f.y * inv) & 255) << 8)
               | ((__float2int_rn(f.z * inv) & 255) << 16)
               | ((__float2int_rn(f.w * inv) & 255) << 24);
    }
    float s_e   = (nt == 2) ? -2.f : -1.f;
    float swl_s = s_e * mx * (LOG2E / (127.f * 127.f));
    float m_a   = (nt == 2) ?  2.f :  1.f;
    float b_a   = (nt == 2) ? -1.f :  0.f;

    // ---- stage embedding half of x: xls[b][0:128] = bf16(word_emb[sid[b]])
    {
        int b  = tid >> 3;          // 0..63
        int c8 = tid & 7;           // 16 floats per thread
        int sid = sentences[t * 64 + b];
        const float4* ep = reinterpret_cast<const float4*>(
            word_emb + (size_t)sid * EMB + c8 * 16);
        float4 e0 = ep[0], e1 = ep[1], e2 = ep[2], e3 = ep[3];
        short8 v0, v1;
        v0[0] = (short)f2bfu(e0.x); v0[1] = (short)f2bfu(e0.y);
        v0[2] = (short)f2bfu(e0.z); v0[3] = (short)f2bfu(e0.w);
        v0[4] = (short)f2bfu(e1.x); v0[5] = (short)f2bfu(e1.y);
        v0[6] = (short)f2bfu(e1.z); v0[7] = (short)f2bfu(e1.w);
        v1[0] = (short)f2bfu(e2.x); v1[1] = (short)f2bfu(e2.y);
        v1[2] = (short)f2bfu(e2.z); v1[3] = (short)f2bfu(e2.w);
        v1[4] = (short)f2bfu(e3.x); v1[5] = (short)f2bfu(e3.y);
        v1[6] = (short)f2bfu(e3.z); v1[7] = (short)f2bfu(e3.w);
        *reinterpret_cast<short8*>(&xls[b][c8 * 16])     = v0;
        *reinterpret_cast<short8*>(&xls[b][c8 * 16 + 8]) = v1;
    }

    if (tid < 64) { reinterpret_cast<int*>(hv)[tid] = 0; }

    float cst = 0.f;
    int cid0 = words[t];
    int cid1 = words[SENT_LEN + t];
    float pl0 = pre8[(size_t)cid0 * 512 + tid];   // this lane's gate pre-input (folded)
    float pl1 = pre8[(size_t)cid1 * 512 + tid];
    int ci2 = words[2 * SENT_LEN + t];
    int ci3 = words[3 * SENT_LEN + t];
    __syncthreads();

    for (int u = 0; u < 512; u++) {          // steps 2u (A), 2u+1 (B)
        float pf0 = pre8[(size_t)ci2 * 512 + tid];
        float pf1 = pre8[(size_t)ci3 * 512 + tid];
        ci2 = words[(((u << 1) + 4) & 1023) * SENT_LEN + t];
        ci3 = words[(((u << 1) + 5) & 1023) * SENT_LEN + t];

        {   // step A: read hv[0] -> write hv[1]
            const i32x4* hp = reinterpret_cast<const i32x4*>(hv[0]);
            int a0 = 0, a1 = 0, a2 = 0, a3 = 0;
#pragma unroll
            for (int q = 0; q < 8; q++) {
                i32x4 hq = hp[q];
                a0 = __builtin_amdgcn_sdot4(hq.x, wqr[q * 4 + 0], a0, false);
                a1 = __builtin_amdgcn_sdot4(hq.y, wqr[q * 4 + 1], a1, false);
                a2 = __builtin_amdgcn_sdot4(hq.z, wqr[q * 4 + 2], a2, false);
                a3 = __builtin_amdgcn_sdot4(hq.w, wqr[q * 4 + 3], a3, false);
            }
            int s = (a0 + a1) + (a2 + a3);
            float e  = __builtin_amdgcn_exp2f(fmaf((float)s, swl_s, pl0));
            float av = m_a * rcpf(1.f + e) + b_a;     // own gate's nonlinearity
            float qi = qbcast<0>(av);                 // sig(i)
            float qf = qbcast<1>(av);                 // sig(f)
            float qg = qbcast<2>(av);                 // tanh(g)
            float qo = qbcast<3>(av);                 // sig(o)
            float c  = fmaf(qf, cst, qi * qg);
            cst = c;
            float tc = 2.f * rcpf(1.f + __builtin_amdgcn_exp2f(N2LOG2E * c)) - 1.f;
            float h  = qo * tc;
            if (nt == 0)
                hv[1][j] = (signed char)__float2int_rn(h * 127.f);
            block_sync_lds();
        }
        {   // step B: read hv[1] -> write hv[0]
            const i32x4* hp = reinterpret_cast<const i32x4*>(hv[1]);
            int a0 = 0, a1 = 0, a2 = 0, a3 = 0;
#pragma unroll
            for (int q = 0; q < 8; q++) {
                i32x4 hq = hp[q];
                a0 = __builtin_amdgcn_sdot4(hq.x, wqr[q * 4 + 0], a0, false);
                a1 = __builtin_amdgcn_sdot4(hq.y, wqr[q * 4 + 1], a1, false);
                a2 = __builtin_amdgcn_sdot4(hq.z, wqr[q * 4 + 2], a2, false);
                a3 = __builtin_amdgcn_sdot4(hq.w, wqr[q * 4 + 3], a3, false);
            }
            int s = (a0 + a1) + (a2 + a3);
            float e  = __builtin_amdgcn_exp2f(fmaf((float)s, swl_s, pl1));
            float av = m_a * rcpf(1.f + e) + b_a;
            float qi = qbcast<0>(av);
            float qf = qbcast<1>(av);
            float qg = qbcast<2>(av);
            float qo = qbcast<3>(av);
            float c  = fmaf(qf, cst, qi * qg);
            cst = c;
            float tc = 2.f * rcpf(1.f + __builtin_amdgcn_exp2f(N2LOG2E * c)) - 1.f;
            float h  = qo * tc;
            if (nt == 0) {
                hv[0][j] = (signed char)__float2int_rn(h * 127.f);
                if ((u & 7) == 7)
                    xls[u >> 3][128 + j] = f2bfu(h);   // x row's char half (bf16)
            }
            block_sync_lds();
        }
        pl0 = pf0; pl1 = pf1;
    }

    // ---- fused XW GEMM epilogue (64 rows x 1024 gates, K=256).
    // Wave w: m-tile mt = w&3, j-tiles jt = (w>>2), +2, ... (8 of 16).
    // A frags from xls (reused across j-tiles); B frags COALESCED from wihbF:
    // frag base ((jt*4+n2)*8+kt)*64, + lane -> contiguous 1KB per instruction.
    {
        int l15 = lane & 15, lq = lane >> 4;
        int mt  = w & 3;
        short8 af[8];
#pragma unroll
        for (int kt = 0; kt < 8; kt++)
            af[kt] = *reinterpret_cast<const short8*>(&xls[mt * 16 + l15][kt * 32 + lq * 8]);
        const short8* bF = reinterpret_cast<const short8*>(wihb);
#pragma unroll 1
        for (int jt = (w >> 2); jt < 16; jt += 2) {
            int j0 = jt * 16;
            const short8* bJ = bF + (size_t)jt * 4 * 8 * 64 + lane;
            f32x4 acc[4] = {{0.f,0.f,0.f,0.f},{0.f,0.f,0.f,0.f},
                            {0.f,0.f,0.f,0.f},{0.f,0.f,0.f,0.f}};
#pragma unroll
            for (int kt = 0; kt < 8; kt++) {
#pragma unroll
                for (int n2 = 0; n2 < 4; n2++) {
                    short8 bf = bJ[(n2 * 8 + kt) * 64];
                    acc[n2] = __builtin_amdgcn_mfma_f32_16x16x32_bf16(
                        af[kt], bf, acc[n2], 0, 0, 0);
                }
            }
            float bb[4];
#pragma unroll
            for (int n2 = 0; n2 < 4; n2++)
                bb[n2] = bih_w[n2 * 256 + j0 + l15] + bhh_w[n2 * 256 + j0 + l15];
#pragma unroll
            for (int r = 0; r < 4; r++) {
                int br = mt * 16 + lq * 4 + r;       // chain index within this t
                uint2 o;
                o.x = (unsigned)f2bfu((acc[0][r] + bb[0]) * LOG2E)
                    | ((unsigned)f2bfu((acc[1][r] + bb[1]) * LOG2E) << 16);
                o.y = (unsigned)f2bfu((acc[2][r] + bb[2]) * LOG2E)
                    | ((unsigned)f2bfu((acc[3][r] + bb[3]) * LOG2E) << 16);
                xw8[((size_t)br * SENT_LEN + t) * 256 + j0 + l15] = o;
            }
        }
    }
}

// ---------------- K4: word LSTM. 64 blocks x 1 chain, 1024 threads (16 waves).
// K=64 native i8 MFMA: 16 instr/wave/step (was 32) — halves the matrix-pipe issue.
__global__ __launch_bounds__(1024, 1) void word_lstm(
        const uint2* __restrict__ xw8, const signed char* __restrict__ wq,
        const float* __restrict__ sw, float* __restrict__ h_out) {
    int b    = blockIdx.x;               // chain 0..63
    int tid  = threadIdx.x;
    int lane = tid & 63, w = tid >> 6;   // 16 waves
    int l15  = lane & 15, lq = lane >> 4;
    int j    = w * 16 + l15;

    __shared__ __align__(16) signed char hv[2][256];   // h as i8, dbuf, 512 B

    lng2 bfr[4][4];
    float swl[4];
#pragma unroll
    for (int nt = 0; nt < 4; nt++) {
        int g = nt * 256 + j;
        swl[nt] = sw[g] * (LOG2E / 127.f);
#pragma unroll
        for (int kt = 0; kt < 4; kt++)
            bfr[nt][kt] = reinterpret_cast<const lng2*>(wq + (size_t)g * HID + kt * 64 + lq * 16)[0];
    }
    if (tid < 128) { reinterpret_cast<int*>(hv)[tid] = 0; }

    const uint2* xwb = xw8 + (size_t)b * SENT_LEN * 256;   // this block's stream
    float cst = 0.f;
    uint2 xq0 = xwb[0 * 256 + j];
    uint2 xq1 = xwb[1 * 256 + j];
    uint2 xq2 = xwb[2 * 256 + j];
    uint2 xq3 = xwb[3 * 256 + j];
    __syncthreads();

    for (int u = 0; u < 128; u++) {          // steps 2u (A), 2u+1 (B)
        uint2 xn0 = xwb[((((u << 1) + 4) & 255)) * 256 + j];
        uint2 xn1 = xwb[((((u << 1) + 5) & 255)) * 256 + j];

        {   // step A: read hv[0] -> write hv[1]
            const lng2* hp = reinterpret_cast<const lng2*>(hv[0]);
            i32x4 acc[4] = {};
#pragma unroll
            for (int kt = 0; kt < 4; kt++) {
                lng2 a = hp[kt * 4 + lq];
#pragma unroll
                for (int nt = 0; nt < 4; nt++)
                    acc[nt] = mfma_i8_k64(a, bfr[nt][kt], acc[nt]);
            }
            float gi = (float)acc[0][0] * swl[0] + bf_lo(xq0.x);
            float gf = (float)acc[1][0] * swl[1] + bf_hi(xq0.x);
            float gg = (float)acc[2][0] * swl[2] + bf_lo(xq0.y);
            float go = (float)acc[3][0] * swl[3] + bf_hi(xq0.y);
            float h = lstm_act(gi, gf, gg, go, cst);
            if (lq == 0) {
                h_out[((size_t)(u << 1) * SENT_BATCH + b) * HID + j] = h;
                hv[1][j] = (signed char)__float2int_rn(h * 127.f);
            }
            block_sync_lds();
        }
        {   // step B: read hv[1] -> write hv[0]
            const lng2* hp = reinterpret_cast<const lng2*>(hv[1]);
            i32x4 acc[4] = {};
#pragma unroll
            for (int kt = 0; kt < 4; kt++) {
                lng2 a = hp[kt * 4 + lq];
#pragma unroll
                for (int nt = 0; nt < 4; nt++)
                    acc[nt] = mfma_i8_k64(a, bfr[nt][kt], acc[nt]);
            }
            float gi = (float)acc[0][0] * swl[0] + bf_lo(xq1.x);
            float gf = (float)acc[1][0] * swl[1] + bf_hi(xq1.x);
            float gg = (float)acc[2][0] * swl[2] + bf_lo(xq1.y);
            float go = (float)acc[3][0] * swl[3] + bf_hi(xq1.y);
            float h = lstm_act(gi, gf, gg, go, cst);
            if (lq == 0) {
                h_out[((size_t)((u << 1) + 1) * SENT_BATCH + b) * HID + j] = h;
                hv[0][j] = (signed char)__float2int_rn(h * 127.f);
            }
            block_sync_lds();
        }
        xq0 = xq2; xq1 = xq3; xq2 = xn0; xq3 = xn1;
    }
}

// ---------------- K5: tag projection + log_softmax. 8 rows/block (W_tag staging amortized).
__global__ __launch_bounds__(256) void tag_logsoftmax(
        const float* __restrict__ h_out, const float* __restrict__ W_tag,
        const float* __restrict__ b_tag, float* __restrict__ out) {
    __shared__ float wt_s[TAGS * 257];      // 51.4 KB
    __shared__ float hr_s[8 * HID];         // 8 KB
    int tid = threadIdx.x;
    int row0 = blockIdx.x * 8;
#pragma unroll 2
    for (int i = 0; i < TAGS; i++) wt_s[i * 257 + tid] = W_tag[i * HID + tid];
#pragma unroll
    for (int w = 0; w < 8; w++) hr_s[w * HID + tid] = h_out[(size_t)(row0 + w) * HID + tid];
    __syncthreads();

    int w4 = tid >> 6, l = tid & 63;
#pragma unroll
    for (int rep = 0; rep < 2; rep++) {
        int w = rep * 4 + w4;
        float acc = 0.f;
        if (l < TAGS) {
            acc = b_tag[l];
            const float* hr = hr_s + w * HID;
            const float* wr = wt_s + l * 257;
#pragma unroll 4
            for (int k = 0; k < HID; k++) acc += hr[k] * wr[k];
        }
        float m = (l < TAGS) ? acc : -1e30f;
#pragma unroll
        for (int off = 32; off; off >>= 1) m = fmaxf(m, __shfl_xor(m, off, 64));
        float e = (l < TAGS) ? __builtin_amdgcn_exp2f((acc - m) * LOG2E) : 0.f;
        float ssum = e;
#pragma unroll
        for (int off = 32; off; off >>= 1) ssum += __shfl_xor(ssum, off, 64);
        float lse = m + __logf(ssum);
        if (l < TAGS) out[(size_t)(row0 + w) * TAGS + l] = acc - lse;
    }
}

extern "C" void kernel_launch(void* const* d_in, const int* in_sizes, int n_in,
                              void* d_out, int out_size, void* d_ws, size_t ws_size,
                              hipStream_t stream) {
    (void)in_sizes; (void)n_in; (void)out_size; (void)ws_size;
    const int*   sentences = (const int*)d_in[0];
    const int*   words     = (const int*)d_in[1];
    const float* word_emb  = (const float*)d_in[4];
    const float* char_emb  = (const float*)d_in[5];
    const float* Wih_c     = (const float*)d_in[6];
    const float* Whh_c     = (const float*)d_in[7];
    const float* bih_c     = (const float*)d_in[8];
    const float* bhh_c     = (const float*)d_in[9];
    const float* Wih_w     = (const float*)d_in[10];
    const float* Whh_w     = (const float*)d_in[11];
    const float* bih_w     = (const float*)d_in[12];
    const float* bhh_w     = (const float*)d_in[13];
    const float* W_tag     = (const float*)d_in[14];
    const float* b_tag     = (const float*)d_in[15];
    float* out = (float*)d_out;

    char* ws = (char*)d_ws;
    size_t off = 0;
    float* pre8 = (float*)(ws + off);                 off += 128 * 512 * sizeof(float);      // 256 KB
    signed char* wq = (signed char*)(ws + off);       off += 1024 * 256;                     // 256 KB
    float* sw = (float*)(ws + off);                   off += 1024 * sizeof(float);           // 4 KB
    unsigned short* wihb = (unsigned short*)(ws + off); off += (size_t)1024 * K_IN * 2;      // 512 KB (fragment order)
    off = (off + 255) & ~(size_t)255;
    uint2* xw8 = (uint2*)(ws + off);                  off += (size_t)SENT_LEN * SENT_BATCH * 256 * sizeof(uint2);  // 33.5 MB
    float* h_out = (float*)(ws + off);                off += (size_t)SENT_LEN * SENT_BATCH * HID * sizeof(float);  // 16.8 MB

    hipLaunchKernelGGL(prep_char, dim3(128), dim3(512), 0, stream,
                       Wih_c, char_emb, bih_c, bhh_c, pre8);
    hipLaunchKernelGGL(prep_wq, dim3(1024), dim3(64), 0, stream, Whh_w, Wih_w, wq, sw, wihb);
    hipLaunchKernelGGL(char_lstm, dim3(256), dim3(512), 0, stream,
                       words, Whh_c, pre8, sentences, word_emb, wihb, bih_w, bhh_w, xw8);
    hipLaunchKernelGGL(word_lstm, dim3(SENT_BATCH), dim3(1024), 0, stream,
                       xw8, wq, sw, h_out);
    hipLaunchKernelGGL(tag_logsoftmax, dim3((SENT_LEN * SENT_BATCH) / 8), dim3(256), 0, stream,
                       h_out, W_tag, b_tag, out);
}